// Round 21
// baseline (390.673 us; speedup 1.0000x reference)
//
#include <hip/hip_runtime.h>
#include <stdint.h>

#define N_NODES 100000
#define N_EDGES 600000
#define HID 128
#define OUT_C 64
#define NELEMS 12800000      // 100000*128
#define BN_EPS 1e-5f
#define LP 136               // LDS row pitch in bf16 elems

typedef short bf16x8 __attribute__((ext_vector_type(8)));
typedef float f32x4 __attribute__((ext_vector_type(4)));

__device__ __forceinline__ unsigned short f2bf(float f) {   // RNE float->bf16
  uint32_t u = __float_as_uint(f);
  uint32_t r = u + 0x7FFFu + ((u >> 16) & 1u);
  return (unsigned short)(r >> 16);
}
__device__ __forceinline__ float bf_lo(uint32_t u) { return __uint_as_float(u << 16); }
__device__ __forceinline__ float bf_hi(uint32_t u) { return __uint_as_float(u & 0xFFFF0000u); }

// ---------------- threefry2x32 (matches JAX) ----------------
__device__ __host__ __forceinline__ void threefry2x32(uint32_t k0, uint32_t k1,
                                                      uint32_t x0, uint32_t x1,
                                                      uint32_t& o0, uint32_t& o1) {
  uint32_t ks0 = k0, ks1 = k1, ks2 = k0 ^ k1 ^ 0x1BD11BDAu;
  x0 += ks0; x1 += ks1;
#define TFR(r) { x0 += x1; x1 = (x1 << (r)) | (x1 >> (32 - (r))); x1 ^= x0; }
  TFR(13) TFR(15) TFR(26) TFR(6)
  x0 += ks1; x1 += ks2 + 1u;
  TFR(17) TFR(29) TFR(16) TFR(24)
  x0 += ks2; x1 += ks0 + 2u;
  TFR(13) TFR(15) TFR(26) TFR(6)
  x0 += ks0; x1 += ks1 + 3u;
  TFR(17) TFR(29) TFR(16) TFR(24)
  x0 += ks1; x1 += ks2 + 4u;
  TFR(13) TFR(15) TFR(26) TFR(6)
  x0 += ks2; x1 += ks0 + 5u;
#undef TFR
  o0 = x0; o1 = x1;
}

__device__ __forceinline__ uint32_t jax_bits32(uint32_t k0, uint32_t k1, uint32_t i) {
  uint32_t b0, b1;
  threefry2x32(k0, k1, 0u, i, b0, b1);
  return b0 ^ b1;
}

// morton spread: bit t -> bit 2t (16-bit input)
__device__ __forceinline__ uint32_t spread16(uint32_t x) {
  x = (x | (x << 8)) & 0x00FF00FFu;
  x = (x | (x << 4)) & 0x0F0F0F0Fu;
  x = (x | (x << 2)) & 0x33333333u;
  x = (x | (x << 1)) & 0x55555555u;
  return x;
}

// ---------------- dropout masks for BOTH layers (full-occupancy pure-VALU threefry)
// wave per node; lane handles channels 2l, 2l+1; ballot + morton pack (r16-verified).
// mask[node*4+q] bit b = keep(channel 32q+b).
__global__ __launch_bounds__(256) void gen_masks(unsigned int* __restrict__ mask1,
                                                 unsigned int* __restrict__ mask2,
                                                 uint32_t a0, uint32_t a1,
                                                 uint32_t b0, uint32_t b1) {
  const int node = blockIdx.x * 4 + (threadIdx.x >> 6);
  const int lane = threadIdx.x & 63;
  uint32_t i0 = (uint32_t)(node * 128 + lane * 2);
  uint32_t r0 = jax_bits32(a0, a1, i0);
  uint32_t r1 = jax_bits32(a0, a1, i0 + 1);
  unsigned long long m0 = __ballot(!(r0 >> 31));   // keep <=> top bit 0
  unsigned long long m1 = __ballot(!(r1 >> 31));
  uint32_t s0 = jax_bits32(b0, b1, i0);
  uint32_t s1 = jax_bits32(b0, b1, i0 + 1);
  unsigned long long n0 = __ballot(!(s0 >> 31));
  unsigned long long n1 = __ballot(!(s1 >> 31));
  if ((lane & 15) == 0) {
    int q = lane >> 4;
    mask1[node * 4 + q] = spread16((uint32_t)(m0 >> lane) & 0xFFFFu)
                        | (spread16((uint32_t)(m1 >> lane) & 0xFFFFu) << 1);
    mask2[node * 4 + q] = spread16((uint32_t)(n0 >> lane) & 0xFFFFu)
                        | (spread16((uint32_t)(n1 >> lane) & 0xFFFFu) << 1);
  }
}

// ---------------- one-time W transpose+cast for W2+W3 in one launch ----------------
__global__ __launch_bounds__(256) void transpose_w23(const float* __restrict__ W2,
                                                     const float* __restrict__ W3,
                                                     unsigned short* __restrict__ Wt2,
                                                     unsigned short* __restrict__ Wt3) {
  int idx = blockIdx.x * 256 + threadIdx.x;        // 0 .. 2*16384
  const float* W = (idx < 16384) ? W2 : W3;
  unsigned short* out = (idx < 16384) ? Wt2 : Wt3;
  int e = idx & 16383;
  int k = e >> 7, c = e & 127;
  out[c * 128 + k] = f2bf(W[e]);
}

// ---------------- MFMA GEMM core (LDS-staged, layer-1 + jk) ----------------
__device__ __forceinline__ void stage_Wt(const float* __restrict__ W,
                                         unsigned short* Wt, int tid) {
#pragma unroll
  for (int i = 0; i < 16; ++i) {            // 4096 float4 = 128 k x 32 cq
    int f4 = tid + i * 256;
    int k = f4 >> 5;
    int cq = f4 & 31;
    float4 w = *(const float4*)(W + k * 128 + cq * 4);
    Wt[(cq * 4 + 0) * LP + k] = f2bf(w.x);
    Wt[(cq * 4 + 1) * LP + k] = f2bf(w.y);
    Wt[(cq * 4 + 2) * LP + k] = f2bf(w.z);
    Wt[(cq * 4 + 3) * LP + k] = f2bf(w.w);
  }
}

__device__ __forceinline__ void mfma_compute_store(const unsigned short* At,
                                                   const unsigned short* Wt,
                                                   unsigned short* __restrict__ O,
                                                   int rbase, int tid) {
  const int lane = tid & 63;
  const int wv = tid >> 6;
  const int m = lane & 15;
  const int kg = lane >> 4;
  f32x4 acc0 = {0,0,0,0}, acc1 = {0,0,0,0}, acc2 = {0,0,0,0}, acc3 = {0,0,0,0};
  f32x4 acc4 = {0,0,0,0}, acc5 = {0,0,0,0}, acc6 = {0,0,0,0}, acc7 = {0,0,0,0};
  const unsigned short* Arow = At + (wv * 16 + m) * LP;
#pragma unroll
  for (int ks = 0; ks < 4; ++ks) {
    bf16x8 af = *(const bf16x8*)(Arow + ks * 32 + kg * 8);
#define MF(n, accn) { bf16x8 bfr = *(const bf16x8*)(Wt + (n * 16 + m) * LP + ks * 32 + kg * 8); \
    accn = __builtin_amdgcn_mfma_f32_16x16x32_bf16(af, bfr, accn, 0, 0, 0); }
    MF(0, acc0) MF(1, acc1) MF(2, acc2) MF(3, acc3)
    MF(4, acc4) MF(5, acc5) MF(6, acc6) MF(7, acc7)
#undef MF
  }
#define ST(n, accn) {                                                       \
  _Pragma("unroll")                                                         \
  for (int j = 0; j < 4; ++j) {                                             \
    int grow = rbase + wv * 16 + kg * 4 + j;                                \
    if (grow < N_NODES) O[(size_t)grow * 128 + n * 16 + m] = f2bf(accn[j]); \
  } }
  ST(0, acc0) ST(1, acc1) ST(2, acc2) ST(3, acc3)
  ST(4, acc4) ST(5, acc5) ST(6, acc6) ST(7, acc7)
#undef ST
}

// plain (layer 1): O = bf16(A) @ bf16(W), O stored bf16
__global__ __launch_bounds__(256) void gemm_mfma(const float* __restrict__ A,
                                                 const float* __restrict__ W,
                                                 unsigned short* __restrict__ O) {
  __shared__ __align__(16) unsigned short Wt[128 * LP];
  __shared__ __align__(16) unsigned short At[64 * LP];
  const int tid = threadIdx.x;
  const int rbase = blockIdx.x * 64;
  stage_Wt(W, Wt, tid);
#pragma unroll
  for (int i = 0; i < 8; ++i) {             // 2048 float4 = 64 r x 32 cq
    int f4 = tid + i * 256;
    int r = f4 >> 5;
    int cq = f4 & 31;
    int grow = rbase + r;
    if (grow >= N_NODES) grow = N_NODES - 1;
    float4 a = *(const float4*)(A + (size_t)grow * 128 + cq * 4);
    uint32_t p0 = (uint32_t)f2bf(a.x) | ((uint32_t)f2bf(a.y) << 16);
    uint32_t p1 = (uint32_t)f2bf(a.z) | ((uint32_t)f2bf(a.w) << 16);
    *(uint2*)(At + r * LP + cq * 4) = make_uint2(p0, p1);
  }
  __syncthreads();
  mfma_compute_store(At, Wt, O, rbase, tid);
}

// fused (layers 2,3): LDS-FREE. Lane (m,kg) owns row wv*16+m.
// BN(scale/shift)+ReLU -> Xb bf16; MASK-dropout -> bf16 A-fragments;
// B-fragments from pre-transposed global bf16 Wt[c][k] (pitch 128).
__global__ __launch_bounds__(256) void gemm_mfma_fused(const float* __restrict__ AGG,
                                                       const float2* __restrict__ ss,
                                                       const unsigned short* __restrict__ Wt,
                                                       const unsigned int* __restrict__ mask,
                                                       unsigned int* __restrict__ Xb,
                                                       unsigned short* __restrict__ O) {
  const int tid = threadIdx.x;
  const int lane = tid & 63;
  const int wv = tid >> 6;
  const int m = lane & 15;
  const int kg = lane >> 4;
  const int rbase = blockIdx.x * 64;
  int row = rbase + wv * 16 + m;
  bool valid = row < N_NODES;
  int rowc = valid ? row : N_NODES - 1;
  const float* Ar = AGG + (size_t)rowc * 128 + kg * 8;
  uint4 mwv = *(const uint4*)(mask + (size_t)rowc * 4);
  bf16x8 af0, af1, af2, af3;
#define LDF(ksc, mw, afk) {                                                    \
    float4 a0 = *(const float4*)(Ar + ksc);                                    \
    float4 a1 = *(const float4*)(Ar + ksc + 4);                                \
    const float2* ssp = ss + ksc + kg * 8;                                     \
    float av[8] = {a0.x, a0.y, a0.z, a0.w, a1.x, a1.y, a1.z, a1.w};            \
    unsigned short yb[8];                                                      \
    _Pragma("unroll")                                                          \
    for (int jj = 0; jj < 8; ++jj) {                                           \
      float2 sv = ssp[jj];                                                     \
      float yv = fmaxf(fmaf(av[jj], sv.x, sv.y), 0.f);                         \
      yb[jj] = f2bf(yv);                                                       \
      bool keep = (mw >> (kg * 8 + jj)) & 1u;                                  \
      afk[jj] = (short)f2bf(keep ? 2.f * yv : 0.f);                            \
    }                                                                          \
    if (valid) {                                                               \
      uint4 yp;                                                                \
      yp.x = (uint32_t)yb[0] | ((uint32_t)yb[1] << 16);                        \
      yp.y = (uint32_t)yb[2] | ((uint32_t)yb[3] << 16);                        \
      yp.z = (uint32_t)yb[4] | ((uint32_t)yb[5] << 16);                        \
      yp.w = (uint32_t)yb[6] | ((uint32_t)yb[7] << 16);                        \
      *(uint4*)(Xb + (size_t)row * 64 + (ksc) / 2 + kg * 4) = yp;              \
    } }
  LDF(0, mwv.x, af0) LDF(32, mwv.y, af1) LDF(64, mwv.z, af2) LDF(96, mwv.w, af3)
#undef LDF
  f32x4 acc0 = {0,0,0,0}, acc1 = {0,0,0,0}, acc2 = {0,0,0,0}, acc3 = {0,0,0,0};
  f32x4 acc4 = {0,0,0,0}, acc5 = {0,0,0,0}, acc6 = {0,0,0,0}, acc7 = {0,0,0,0};
  const unsigned short* Wm = Wt + m * 128 + kg * 8;
#define MFMA_ALL(afk, ksc)                                                              \
  acc0 = __builtin_amdgcn_mfma_f32_16x16x32_bf16(afk, *(const bf16x8*)(Wm + 0 * 2048 + ksc), acc0, 0, 0, 0); \
  acc1 = __builtin_amdgcn_mfma_f32_16x16x32_bf16(afk, *(const bf16x8*)(Wm + 1 * 2048 + ksc), acc1, 0, 0, 0); \
  acc2 = __builtin_amdgcn_mfma_f32_16x16x32_bf16(afk, *(const bf16x8*)(Wm + 2 * 2048 + ksc), acc2, 0, 0, 0); \
  acc3 = __builtin_amdgcn_mfma_f32_16x16x32_bf16(afk, *(const bf16x8*)(Wm + 3 * 2048 + ksc), acc3, 0, 0, 0); \
  acc4 = __builtin_amdgcn_mfma_f32_16x16x32_bf16(afk, *(const bf16x8*)(Wm + 4 * 2048 + ksc), acc4, 0, 0, 0); \
  acc5 = __builtin_amdgcn_mfma_f32_16x16x32_bf16(afk, *(const bf16x8*)(Wm + 5 * 2048 + ksc), acc5, 0, 0, 0); \
  acc6 = __builtin_amdgcn_mfma_f32_16x16x32_bf16(afk, *(const bf16x8*)(Wm + 6 * 2048 + ksc), acc6, 0, 0, 0); \
  acc7 = __builtin_amdgcn_mfma_f32_16x16x32_bf16(afk, *(const bf16x8*)(Wm + 7 * 2048 + ksc), acc7, 0, 0, 0);
  MFMA_ALL(af0, 0) MFMA_ALL(af1, 32) MFMA_ALL(af2, 64) MFMA_ALL(af3, 96)
#undef MFMA_ALL
#pragma unroll
  for (int j = 0; j < 4; ++j) {
    int orow = rbase + wv * 16 + kg * 4 + j;
    if (orow < N_NODES) {
      unsigned short* op = O + (size_t)orow * 128 + m;
      op[0 * 16] = f2bf(acc0[j]); op[1 * 16] = f2bf(acc1[j]);
      op[2 * 16] = f2bf(acc2[j]); op[3 * 16] = f2bf(acc3[j]);
      op[4 * 16] = f2bf(acc4[j]); op[5 * 16] = f2bf(acc5[j]);
      op[6 * 16] = f2bf(acc6[j]); op[7 * 16] = f2bf(acc7[j]);
    }
  }
}

// ---------------- CSR build ----------------
__global__ __launch_bounds__(256) void csr_count(const int* __restrict__ ei,
                                                 int* __restrict__ cnt) {
  int e = blockIdx.x * 256 + threadIdx.x;
  if (e < N_EDGES) atomicAdd(&cnt[ei[e + N_EDGES]], 1);
}

__global__ __launch_bounds__(256) void scan_blocks(int* __restrict__ cnt,
                                                   int* __restrict__ bsum) {
  __shared__ int tmp[256];
  int tid = threadIdx.x;
  int i = blockIdx.x * 256 + tid;
  int v = (i < N_NODES) ? cnt[i] : 0;
  tmp[tid] = v;
  __syncthreads();
  for (int off = 1; off < 256; off <<= 1) {
    int t = (tid >= off) ? tmp[tid - off] : 0;
    __syncthreads();
    if (tid >= off) tmp[tid] += t;
    __syncthreads();
  }
  if (i < N_NODES) cnt[i] = tmp[tid] - v;
  if (tid == 255) bsum[blockIdx.x] = tmp[255];
}

__global__ __launch_bounds__(512) void scan_bsum(int* __restrict__ bsum, int nb) {
  __shared__ int tmp[512];
  int tid = threadIdx.x;
  int v = (tid < nb) ? bsum[tid] : 0;
  tmp[tid] = v;
  __syncthreads();
  for (int off = 1; off < 512; off <<= 1) {
    int t = (tid >= off) ? tmp[tid - off] : 0;
    __syncthreads();
    if (tid >= off) tmp[tid] += t;
    __syncthreads();
  }
  if (tid < nb) bsum[tid] = tmp[tid] - v;
}

__global__ __launch_bounds__(256) void add_offsets(int* __restrict__ cnt,
                                                   const int* __restrict__ bsum,
                                                   int* __restrict__ row_ptr) {
  int i = blockIdx.x * 256 + threadIdx.x;
  if (i < N_NODES) {
    int r = cnt[i] + bsum[blockIdx.x];
    row_ptr[i] = r;
    cnt[i] = r;
  }
  if (i == 0) row_ptr[N_NODES] = N_EDGES;
}

__global__ __launch_bounds__(256) void csr_fill(const int* __restrict__ ei,
                                                const float* __restrict__ ew,
                                                int* __restrict__ cursor,
                                                int2* __restrict__ edges) {
  int e = blockIdx.x * 256 + threadIdx.x;
  if (e < N_EDGES) {
    int d = ei[e + N_EDGES];
    int p = atomicAdd(&cursor[d], 1);
    edges[p] = make_int2(ei[e], __float_as_int(ew[e]));
  }
}

// ---------------- gather aggregation + (optional) fused BN stats
// HALF-WAVE per node: 32 lanes x uint2 (4 channels each); 8 nodes per 256-thr block.
template <bool STATS>
__global__ __launch_bounds__(256) void gather_agg(const unsigned int* __restrict__ Hb,
                                                  const int* __restrict__ row_ptr,
                                                  const int2* __restrict__ edges,
                                                  const float* __restrict__ bias,
                                                  float* __restrict__ AGG,
                                                  float* __restrict__ partials) {
  const int hw = threadIdx.x >> 5;          // 0..7 half-wave slot
  const int l32 = threadIdx.x & 31;         // lane within half-wave
  const int node = blockIdx.x * 8 + hw;
  float4 acc = *(const float4*)(bias + l32 * 4);
  const int beg = row_ptr[node];
  const int end = row_ptr[node + 1];
  const unsigned int* Hp = Hb + l32 * 2;
  int j = beg;
  for (; j + 3 < end; j += 4) {
    int2 e0 = edges[j + 0];
    int2 e1 = edges[j + 1];
    int2 e2 = edges[j + 2];
    int2 e3 = edges[j + 3];
    uint2 u0 = *(const uint2*)(Hp + (size_t)e0.x * 64);
    uint2 u1 = *(const uint2*)(Hp + (size_t)e1.x * 64);
    uint2 u2 = *(const uint2*)(Hp + (size_t)e2.x * 64);
    uint2 u3 = *(const uint2*)(Hp + (size_t)e3.x * 64);
    float w0 = __int_as_float(e0.y), w1 = __int_as_float(e1.y);
    float w2 = __int_as_float(e2.y), w3 = __int_as_float(e3.y);
    acc.x += w0 * bf_lo(u0.x) + w1 * bf_lo(u1.x) + w2 * bf_lo(u2.x) + w3 * bf_lo(u3.x);
    acc.y += w0 * bf_hi(u0.x) + w1 * bf_hi(u1.x) + w2 * bf_hi(u2.x) + w3 * bf_hi(u3.x);
    acc.z += w0 * bf_lo(u0.y) + w1 * bf_lo(u1.y) + w2 * bf_lo(u2.y) + w3 * bf_lo(u3.y);
    acc.w += w0 * bf_hi(u0.y) + w1 * bf_hi(u1.y) + w2 * bf_hi(u2.y) + w3 * bf_hi(u3.y);
  }
  for (; j < end; ++j) {
    int2 e = edges[j];
    uint2 u = *(const uint2*)(Hp + (size_t)e.x * 64);
    float w = __int_as_float(e.y);
    acc.x += w * bf_lo(u.x);
    acc.y += w * bf_hi(u.x);
    acc.z += w * bf_lo(u.y);
    acc.w += w * bf_hi(u.y);
  }
  *(float4*)(AGG + (size_t)node * 128 + l32 * 4) = acc;

  if (STATS) {
    __shared__ float st[8][256];
    st[hw][l32 * 4 + 0] = acc.x;
    st[hw][l32 * 4 + 1] = acc.y;
    st[hw][l32 * 4 + 2] = acc.z;
    st[hw][l32 * 4 + 3] = acc.w;
    st[hw][128 + l32 * 4 + 0] = acc.x * acc.x;
    st[hw][128 + l32 * 4 + 1] = acc.y * acc.y;
    st[hw][128 + l32 * 4 + 2] = acc.z * acc.z;
    st[hw][128 + l32 * 4 + 3] = acc.w * acc.w;
    __syncthreads();
    float t = 0.f;
#pragma unroll
    for (int g = 0; g < 8; ++g) t += st[g][threadIdx.x];
    unsafeAtomicAdd(&partials[(blockIdx.x & 63) * 256 + threadIdx.x], t);
  }
}

// read 64x256 partials -> ss; re-zero partials for the next layer
__global__ __launch_bounds__(128) void stats_finalize(float* __restrict__ partials,
                                                      const float* __restrict__ g,
                                                      const float* __restrict__ bt,
                                                      float2* __restrict__ ss) {
  int c = threadIdx.x;
  float s = 0.f, q = 0.f;
#pragma unroll 8
  for (int b = 0; b < 64; ++b) {
    s += partials[b * 256 + c];
    q += partials[b * 256 + 128 + c];
  }
#pragma unroll 8
  for (int b = 0; b < 64; ++b) {
    partials[b * 256 + c] = 0.f;
    partials[b * 256 + 128 + c] = 0.f;
  }
  float mu = s * (1.0f / N_NODES);
  float var = fmaxf(q * (1.0f / N_NODES) - mu * mu, 0.f);
  float inv = rsqrtf(var + BN_EPS);
  float sc = g[c] * inv;
  ss[c] = make_float2(sc, bt[c] - mu * sc);
}

// ---------------- jk_final via MFMA (LDS version): jk = max(bf16 X1, bf16 X2, fp32 X3);
// OUT = log_softmax(jk @ Wf + bf). 64 rows/block; A=jk bf16, B=Wf^T bf16 in LDS.
__global__ __launch_bounds__(256) void jk_final_mfma(const unsigned int* __restrict__ X1b,
                                                     const unsigned int* __restrict__ X2b,
                                                     const float* __restrict__ X3,
                                                     const float* __restrict__ Wf,
                                                     const float* __restrict__ bf,
                                                     float* __restrict__ OUT) {
  __shared__ __align__(16) unsigned short Wt[64 * LP];   // Wt[col][k]
  __shared__ __align__(16) unsigned short At[64 * LP];   // jk rows bf16
  const int tid = threadIdx.x;
  const int rbase = blockIdx.x * 64;
#pragma unroll
  for (int i = 0; i < 8; ++i) {             // 2048 float4 = 128 k x 16 cq
    int f4 = tid + i * 256;
    int k = f4 >> 4;
    int cq = f4 & 15;
    float4 w = *(const float4*)(Wf + k * 64 + cq * 4);
    Wt[(cq * 4 + 0) * LP + k] = f2bf(w.x);
    Wt[(cq * 4 + 1) * LP + k] = f2bf(w.y);
    Wt[(cq * 4 + 2) * LP + k] = f2bf(w.z);
    Wt[(cq * 4 + 3) * LP + k] = f2bf(w.w);
  }
#pragma unroll
  for (int i = 0; i < 8; ++i) {             // 2048 quads = 64 r x 32 cq
    int f4 = tid + i * 256;
    int r = f4 >> 5;
    int cq = f4 & 31;
    int grow = rbase + r;
    if (grow >= N_NODES) grow = N_NODES - 1;
    uint2 u1 = *(const uint2*)(X1b + (size_t)grow * 64 + cq * 2);
    uint2 u2 = *(const uint2*)(X2b + (size_t)grow * 64 + cq * 2);
    float4 x3 = *(const float4*)(X3 + (size_t)grow * 128 + cq * 4);
    float m0 = fmaxf(fmaxf(bf_lo(u1.x), bf_lo(u2.x)), x3.x);
    float m1 = fmaxf(fmaxf(bf_hi(u1.x), bf_hi(u2.x)), x3.y);
    float m2 = fmaxf(fmaxf(bf_lo(u1.y), bf_lo(u2.y)), x3.z);
    float m3 = fmaxf(fmaxf(bf_hi(u1.y), bf_hi(u2.y)), x3.w);
    uint32_t p0 = (uint32_t)f2bf(m0) | ((uint32_t)f2bf(m1) << 16);
    uint32_t p1 = (uint32_t)f2bf(m2) | ((uint32_t)f2bf(m3) << 16);
    *(uint2*)(At + r * LP + cq * 4) = make_uint2(p0, p1);
  }
  __syncthreads();
  const int lane = tid & 63;
  const int wv = tid >> 6;
  const int m = lane & 15;
  const int kg = lane >> 4;
  f32x4 acc0 = {0,0,0,0}, acc1 = {0,0,0,0}, acc2 = {0,0,0,0}, acc3 = {0,0,0,0};
  const unsigned short* Arow = At + (wv * 16 + m) * LP;
#pragma unroll
  for (int ks = 0; ks < 4; ++ks) {
    bf16x8 af = *(const bf16x8*)(Arow + ks * 32 + kg * 8);
#define MF(n, accn) { bf16x8 bfr = *(const bf16x8*)(Wt + (n * 16 + m) * LP + ks * 32 + kg * 8); \
    accn = __builtin_amdgcn_mfma_f32_16x16x32_bf16(af, bfr, accn, 0, 0, 0); }
    MF(0, acc0) MF(1, acc1) MF(2, acc2) MF(3, acc3)
#undef MF
  }
  float bf0 = bf[m], bf1 = bf[16 + m], bf2 = bf[32 + m], bf3 = bf[48 + m];
#pragma unroll
  for (int j = 0; j < 4; ++j) {
    int row = rbase + wv * 16 + kg * 4 + j;
    float v0 = acc0[j] + bf0;
    float v1 = acc1[j] + bf1;
    float v2 = acc2[j] + bf2;
    float v3 = acc3[j] + bf3;
    float M = fmaxf(fmaxf(v0, v1), fmaxf(v2, v3));
#pragma unroll
    for (int s = 1; s < 16; s <<= 1) M = fmaxf(M, __shfl_xor(M, s));
    float sum = expf(v0 - M) + expf(v1 - M) + expf(v2 - M) + expf(v3 - M);
#pragma unroll
    for (int s = 1; s < 16; s <<= 1) sum += __shfl_xor(sum, s);
    float ls = M + logf(sum);
    if (row < N_NODES) {
      float* o = OUT + (size_t)row * 64;
      o[m] = v0 - ls;
      o[16 + m] = v1 - ls;
      o[32 + m] = v2 - ls;
      o[48 + m] = v3 - ls;
    }
  }
}

extern "C" void kernel_launch(void* const* d_in, const int* in_sizes, int n_in,
                              void* d_out, int out_size, void* d_ws, size_t ws_size,
                              hipStream_t stream) {
  const float* x   = (const float*)d_in[0];
  const int*   ei  = (const int*)d_in[1];
  const float* ew  = (const float*)d_in[2];
  const float* W1  = (const float*)d_in[3];
  const float* b1  = (const float*)d_in[4];
  const float* W2  = (const float*)d_in[5];
  const float* b2  = (const float*)d_in[6];
  const float* W3  = (const float*)d_in[7];
  const float* b3  = (const float*)d_in[8];
  const float* g1  = (const float*)d_in[9];
  const float* bt1 = (const float*)d_in[10];
  const float* g2  = (const float*)d_in[11];
  const float* bt2 = (const float*)d_in[12];
  const float* Wf  = (const float*)d_in[13];
  const float* bfb = (const float*)d_in[14];
  float* out = (float*)d_out;

  float* B0 = (float*)d_ws;                // P buffer (bf16 ushort[NELEMS])
  float* B1 = B0 + NELEMS;                 // AGG fp32
  float* B2 = B1 + NELEMS;                 // X1 bf16 (uses half)
  float* B3 = B2 + NELEMS;                 // X2 bf16 (uses half)
  int2* edges = (int2*)(B3 + NELEMS);      // N_EDGES int2
  int* cursor = (int*)(edges + N_EDGES);   // N_NODES
  int* row_ptr = cursor + N_NODES;         // N_NODES+1
  int* bsum = row_ptr + N_NODES + 1;       // 512
  float* partials = (float*)(bsum + 512);  // 64*256 floats (64KB)
  float2* ss1 = (float2*)(partials + 64 * 256);    // 128 float2
  float2* ss2 = ss1 + 128;
  unsigned short* Wt2 = (unsigned short*)(ss2 + 128);  // 128*128 bf16
  unsigned short* Wt3 = Wt2 + 128 * 128;
  unsigned int* mask1 = (unsigned int*)(Wt3 + 128 * 128);  // N_NODES*4 u32
  unsigned int* mask2 = mask1 + N_NODES * 4;
  unsigned short* P = (unsigned short*)B0;
  unsigned int* Pu = (unsigned int*)B0;
  unsigned int* X1b = (unsigned int*)B2;
  unsigned int* X2b = (unsigned int*)B3;

  // JAX partitionable split of key(42)=(0,42): k_i = threefry(key, (0,i)) full pair
  uint32_t k1_0, k1_1, k2_0, k2_1;
  threefry2x32(0u, 42u, 0u, 0u, k1_0, k1_1);
  threefry2x32(0u, 42u, 0u, 1u, k2_0, k2_1);

  const int GEMM_GRID = (N_NODES + 63) / 64;       // 1563
  const int EDGE_GRID = (N_EDGES + 255) / 256;     // 2344
  const int NODE_GRID = (N_NODES + 255) / 256;     // 391
  const int AGG_GRID  = N_NODES / 8;               // 12500 (half-wave per node)
  const int MASK_GRID = N_NODES / 4;               // 25000 (wave per node)
  const int FINAL_GRID = (N_NODES + 63) / 64;      // 1563
  const int TR_GRID = (2 * 128 * 128 + 255) / 256; // 128

  // ---- W2/W3 pre-transpose + dropout masks + CSR build + zero partials
  transpose_w23<<<TR_GRID, 256, 0, stream>>>(W2, W3, Wt2, Wt3);
  gen_masks<<<MASK_GRID, 256, 0, stream>>>(mask1, mask2, k1_0, k1_1, k2_0, k2_1);
  hipMemsetAsync(cursor, 0, N_NODES * sizeof(int), stream);
  hipMemsetAsync(partials, 0, 64 * 256 * sizeof(float), stream);
  csr_count<<<EDGE_GRID, 256, 0, stream>>>(ei, cursor);
  scan_blocks<<<NODE_GRID, 256, 0, stream>>>(cursor, bsum);
  scan_bsum<<<1, 512, 0, stream>>>(bsum, NODE_GRID);
  add_offsets<<<NODE_GRID, 256, 0, stream>>>(cursor, bsum, row_ptr);
  csr_fill<<<EDGE_GRID, 256, 0, stream>>>(ei, ew, cursor, edges);

  // ---- layer 1: P = bf16(x@W1) ; AGG1 = gather(P)+b1 (+stats) ; ss1
  gemm_mfma<<<GEMM_GRID, 256, 0, stream>>>(x, W1, P);
  gather_agg<true><<<AGG_GRID, 256, 0, stream>>>(Pu, row_ptr, edges, b1, B1, partials);
  stats_finalize<<<1, 128, 0, stream>>>(partials, g1, bt1, ss1);
  // ---- layer 2: fused BN1+ReLU (-> X1 bf16) + mask1-dropout + MFMA GEMM W2 -> P
  gemm_mfma_fused<<<GEMM_GRID, 256, 0, stream>>>(B1, ss1, Wt2, mask1, X1b, P);
  gather_agg<true><<<AGG_GRID, 256, 0, stream>>>(Pu, row_ptr, edges, b2, B1, partials);
  stats_finalize<<<1, 128, 0, stream>>>(partials, g2, bt2, ss2);
  // ---- layer 3: fused BN2+ReLU (-> X2 bf16) + mask2-dropout + MFMA GEMM W3 -> P
  gemm_mfma_fused<<<GEMM_GRID, 256, 0, stream>>>(B1, ss2, Wt3, mask2, X2b, P);
  gather_agg<false><<<AGG_GRID, 256, 0, stream>>>(Pu, row_ptr, edges, b3, B1, nullptr);
  // ---- JK max + final linear + log_softmax (MFMA)
  jk_final_mfma<<<FINAL_GRID, 256, 0, stream>>>(X1b, X2b, B1, Wf, bfb, out);
}

// Round 22
// 361.354 us; speedup vs baseline: 1.0811x; 1.0811x over previous
//
#include <hip/hip_runtime.h>
#include <stdint.h>

#define N_NODES 100000
#define N_EDGES 600000
#define HID 128
#define OUT_C 64
#define NELEMS 12800000      // 100000*128
#define BN_EPS 1e-5f
#define LP 136               // LDS row pitch in bf16 elems

typedef short bf16x8 __attribute__((ext_vector_type(8)));
typedef float f32x4 __attribute__((ext_vector_type(4)));

__device__ __forceinline__ unsigned short f2bf(float f) {   // RNE float->bf16
  uint32_t u = __float_as_uint(f);
  uint32_t r = u + 0x7FFFu + ((u >> 16) & 1u);
  return (unsigned short)(r >> 16);
}
__device__ __forceinline__ float bf_lo(uint32_t u) { return __uint_as_float(u << 16); }
__device__ __forceinline__ float bf_hi(uint32_t u) { return __uint_as_float(u & 0xFFFF0000u); }

// ---------------- threefry2x32 (matches JAX) ----------------
__device__ __host__ __forceinline__ void threefry2x32(uint32_t k0, uint32_t k1,
                                                      uint32_t x0, uint32_t x1,
                                                      uint32_t& o0, uint32_t& o1) {
  uint32_t ks0 = k0, ks1 = k1, ks2 = k0 ^ k1 ^ 0x1BD11BDAu;
  x0 += ks0; x1 += ks1;
#define TFR(r) { x0 += x1; x1 = (x1 << (r)) | (x1 >> (32 - (r))); x1 ^= x0; }
  TFR(13) TFR(15) TFR(26) TFR(6)
  x0 += ks1; x1 += ks2 + 1u;
  TFR(17) TFR(29) TFR(16) TFR(24)
  x0 += ks2; x1 += ks0 + 2u;
  TFR(13) TFR(15) TFR(26) TFR(6)
  x0 += ks0; x1 += ks1 + 3u;
  TFR(17) TFR(29) TFR(16) TFR(24)
  x0 += ks1; x1 += ks2 + 4u;
  TFR(13) TFR(15) TFR(26) TFR(6)
  x0 += ks2; x1 += ks0 + 5u;
#undef TFR
  o0 = x0; o1 = x1;
}

__device__ __forceinline__ uint32_t jax_bits32(uint32_t k0, uint32_t k1, uint32_t i) {
  uint32_t b0, b1;
  threefry2x32(k0, k1, 0u, i, b0, b1);
  return b0 ^ b1;
}

// ---------------- one-time W transpose+cast for W2+W3 in one launch ----------------
__global__ __launch_bounds__(256) void transpose_w23(const float* __restrict__ W2,
                                                     const float* __restrict__ W3,
                                                     unsigned short* __restrict__ Wt2,
                                                     unsigned short* __restrict__ Wt3) {
  int idx = blockIdx.x * 256 + threadIdx.x;        // 0 .. 2*16384
  const float* W = (idx < 16384) ? W2 : W3;
  unsigned short* out = (idx < 16384) ? Wt2 : Wt3;
  int e = idx & 16383;
  int k = e >> 7, c = e & 127;
  out[c * 128 + k] = f2bf(W[e]);
}

// ---------------- MFMA GEMM core (LDS-staged, layer-1 + jk) ----------------
__device__ __forceinline__ void stage_Wt(const float* __restrict__ W,
                                         unsigned short* Wt, int tid) {
#pragma unroll
  for (int i = 0; i < 16; ++i) {            // 4096 float4 = 128 k x 32 cq
    int f4 = tid + i * 256;
    int k = f4 >> 5;
    int cq = f4 & 31;
    float4 w = *(const float4*)(W + k * 128 + cq * 4);
    Wt[(cq * 4 + 0) * LP + k] = f2bf(w.x);
    Wt[(cq * 4 + 1) * LP + k] = f2bf(w.y);
    Wt[(cq * 4 + 2) * LP + k] = f2bf(w.z);
    Wt[(cq * 4 + 3) * LP + k] = f2bf(w.w);
  }
}

__device__ __forceinline__ void mfma_compute_store(const unsigned short* At,
                                                   const unsigned short* Wt,
                                                   unsigned short* __restrict__ O,
                                                   int rbase, int tid) {
  const int lane = tid & 63;
  const int wv = tid >> 6;
  const int m = lane & 15;
  const int kg = lane >> 4;
  f32x4 acc0 = {0,0,0,0}, acc1 = {0,0,0,0}, acc2 = {0,0,0,0}, acc3 = {0,0,0,0};
  f32x4 acc4 = {0,0,0,0}, acc5 = {0,0,0,0}, acc6 = {0,0,0,0}, acc7 = {0,0,0,0};
  const unsigned short* Arow = At + (wv * 16 + m) * LP;
#pragma unroll
  for (int ks = 0; ks < 4; ++ks) {
    bf16x8 af = *(const bf16x8*)(Arow + ks * 32 + kg * 8);
#define MF(n, accn) { bf16x8 bfr = *(const bf16x8*)(Wt + (n * 16 + m) * LP + ks * 32 + kg * 8); \
    accn = __builtin_amdgcn_mfma_f32_16x16x32_bf16(af, bfr, accn, 0, 0, 0); }
    MF(0, acc0) MF(1, acc1) MF(2, acc2) MF(3, acc3)
    MF(4, acc4) MF(5, acc5) MF(6, acc6) MF(7, acc7)
#undef MF
  }
#define ST(n, accn) {                                                       \
  _Pragma("unroll")                                                         \
  for (int j = 0; j < 4; ++j) {                                             \
    int grow = rbase + wv * 16 + kg * 4 + j;                                \
    if (grow < N_NODES) O[(size_t)grow * 128 + n * 16 + m] = f2bf(accn[j]); \
  } }
  ST(0, acc0) ST(1, acc1) ST(2, acc2) ST(3, acc3)
  ST(4, acc4) ST(5, acc5) ST(6, acc6) ST(7, acc7)
#undef ST
}

// plain (layer 1): O = bf16(A) @ bf16(W), O stored bf16
__global__ __launch_bounds__(256) void gemm_mfma(const float* __restrict__ A,
                                                 const float* __restrict__ W,
                                                 unsigned short* __restrict__ O) {
  __shared__ __align__(16) unsigned short Wt[128 * LP];
  __shared__ __align__(16) unsigned short At[64 * LP];
  const int tid = threadIdx.x;
  const int rbase = blockIdx.x * 64;
  stage_Wt(W, Wt, tid);
#pragma unroll
  for (int i = 0; i < 8; ++i) {             // 2048 float4 = 64 r x 32 cq
    int f4 = tid + i * 256;
    int r = f4 >> 5;
    int cq = f4 & 31;
    int grow = rbase + r;
    if (grow >= N_NODES) grow = N_NODES - 1;
    float4 a = *(const float4*)(A + (size_t)grow * 128 + cq * 4);
    uint32_t p0 = (uint32_t)f2bf(a.x) | ((uint32_t)f2bf(a.y) << 16);
    uint32_t p1 = (uint32_t)f2bf(a.z) | ((uint32_t)f2bf(a.w) << 16);
    *(uint2*)(At + r * LP + cq * 4) = make_uint2(p0, p1);
  }
  __syncthreads();
  mfma_compute_store(At, Wt, O, rbase, tid);
}

// fused (layers 2,3): LDS-FREE. Lane (m,kg) owns row wv*16+m.
// BN(scale/shift)+ReLU -> Xb bf16; MASK-dropout -> bf16 A-fragments;
// B-fragments from pre-transposed global bf16 Wt[c][k] (pitch 128).
__global__ __launch_bounds__(256) void gemm_mfma_fused(const float* __restrict__ AGG,
                                                       const float2* __restrict__ ss,
                                                       const unsigned short* __restrict__ Wt,
                                                       const unsigned int* __restrict__ mask,
                                                       unsigned int* __restrict__ Xb,
                                                       unsigned short* __restrict__ O) {
  const int tid = threadIdx.x;
  const int lane = tid & 63;
  const int wv = tid >> 6;
  const int m = lane & 15;
  const int kg = lane >> 4;
  const int rbase = blockIdx.x * 64;
  int row = rbase + wv * 16 + m;
  bool valid = row < N_NODES;
  int rowc = valid ? row : N_NODES - 1;
  const float* Ar = AGG + (size_t)rowc * 128 + kg * 8;
  uint4 mwv = *(const uint4*)(mask + (size_t)rowc * 4);
  bf16x8 af0, af1, af2, af3;
#define LDF(ksc, mw, afk) {                                                    \
    float4 a0 = *(const float4*)(Ar + ksc);                                    \
    float4 a1 = *(const float4*)(Ar + ksc + 4);                                \
    const float2* ssp = ss + ksc + kg * 8;                                     \
    float av[8] = {a0.x, a0.y, a0.z, a0.w, a1.x, a1.y, a1.z, a1.w};            \
    unsigned short yb[8];                                                      \
    _Pragma("unroll")                                                          \
    for (int jj = 0; jj < 8; ++jj) {                                           \
      float2 sv = ssp[jj];                                                     \
      float yv = fmaxf(fmaf(av[jj], sv.x, sv.y), 0.f);                         \
      yb[jj] = f2bf(yv);                                                       \
      bool keep = (mw >> (kg * 8 + jj)) & 1u;                                  \
      afk[jj] = (short)f2bf(keep ? 2.f * yv : 0.f);                            \
    }                                                                          \
    if (valid) {                                                               \
      uint4 yp;                                                                \
      yp.x = (uint32_t)yb[0] | ((uint32_t)yb[1] << 16);                        \
      yp.y = (uint32_t)yb[2] | ((uint32_t)yb[3] << 16);                        \
      yp.z = (uint32_t)yb[4] | ((uint32_t)yb[5] << 16);                        \
      yp.w = (uint32_t)yb[6] | ((uint32_t)yb[7] << 16);                        \
      *(uint4*)(Xb + (size_t)row * 64 + (ksc) / 2 + kg * 4) = yp;              \
    } }
  LDF(0, mwv.x, af0) LDF(32, mwv.y, af1) LDF(64, mwv.z, af2) LDF(96, mwv.w, af3)
#undef LDF
  f32x4 acc0 = {0,0,0,0}, acc1 = {0,0,0,0}, acc2 = {0,0,0,0}, acc3 = {0,0,0,0};
  f32x4 acc4 = {0,0,0,0}, acc5 = {0,0,0,0}, acc6 = {0,0,0,0}, acc7 = {0,0,0,0};
  const unsigned short* Wm = Wt + m * 128 + kg * 8;
#define MFMA_ALL(afk, ksc)                                                              \
  acc0 = __builtin_amdgcn_mfma_f32_16x16x32_bf16(afk, *(const bf16x8*)(Wm + 0 * 2048 + ksc), acc0, 0, 0, 0); \
  acc1 = __builtin_amdgcn_mfma_f32_16x16x32_bf16(afk, *(const bf16x8*)(Wm + 1 * 2048 + ksc), acc1, 0, 0, 0); \
  acc2 = __builtin_amdgcn_mfma_f32_16x16x32_bf16(afk, *(const bf16x8*)(Wm + 2 * 2048 + ksc), acc2, 0, 0, 0); \
  acc3 = __builtin_amdgcn_mfma_f32_16x16x32_bf16(afk, *(const bf16x8*)(Wm + 3 * 2048 + ksc), acc3, 0, 0, 0); \
  acc4 = __builtin_amdgcn_mfma_f32_16x16x32_bf16(afk, *(const bf16x8*)(Wm + 4 * 2048 + ksc), acc4, 0, 0, 0); \
  acc5 = __builtin_amdgcn_mfma_f32_16x16x32_bf16(afk, *(const bf16x8*)(Wm + 5 * 2048 + ksc), acc5, 0, 0, 0); \
  acc6 = __builtin_amdgcn_mfma_f32_16x16x32_bf16(afk, *(const bf16x8*)(Wm + 6 * 2048 + ksc), acc6, 0, 0, 0); \
  acc7 = __builtin_amdgcn_mfma_f32_16x16x32_bf16(afk, *(const bf16x8*)(Wm + 7 * 2048 + ksc), acc7, 0, 0, 0);
  MFMA_ALL(af0, 0) MFMA_ALL(af1, 32) MFMA_ALL(af2, 64) MFMA_ALL(af3, 96)
#undef MFMA_ALL
#pragma unroll
  for (int j = 0; j < 4; ++j) {
    int orow = rbase + wv * 16 + kg * 4 + j;
    if (orow < N_NODES) {
      unsigned short* op = O + (size_t)orow * 128 + m;
      op[0 * 16] = f2bf(acc0[j]); op[1 * 16] = f2bf(acc1[j]);
      op[2 * 16] = f2bf(acc2[j]); op[3 * 16] = f2bf(acc3[j]);
      op[4 * 16] = f2bf(acc4[j]); op[5 * 16] = f2bf(acc5[j]);
      op[6 * 16] = f2bf(acc6[j]); op[7 * 16] = f2bf(acc7[j]);
    }
  }
}

// ---------------- CSR build ----------------
__global__ __launch_bounds__(256) void csr_count(const int* __restrict__ ei,
                                                 int* __restrict__ cnt) {
  int e = blockIdx.x * 256 + threadIdx.x;
  if (e < N_EDGES) atomicAdd(&cnt[ei[e + N_EDGES]], 1);
}

__global__ __launch_bounds__(256) void scan_blocks(int* __restrict__ cnt,
                                                   int* __restrict__ bsum) {
  __shared__ int tmp[256];
  int tid = threadIdx.x;
  int i = blockIdx.x * 256 + tid;
  int v = (i < N_NODES) ? cnt[i] : 0;
  tmp[tid] = v;
  __syncthreads();
  for (int off = 1; off < 256; off <<= 1) {
    int t = (tid >= off) ? tmp[tid - off] : 0;
    __syncthreads();
    if (tid >= off) tmp[tid] += t;
    __syncthreads();
  }
  if (i < N_NODES) cnt[i] = tmp[tid] - v;
  if (tid == 255) bsum[blockIdx.x] = tmp[255];
}

__global__ __launch_bounds__(512) void scan_bsum(int* __restrict__ bsum, int nb) {
  __shared__ int tmp[512];
  int tid = threadIdx.x;
  int v = (tid < nb) ? bsum[tid] : 0;
  tmp[tid] = v;
  __syncthreads();
  for (int off = 1; off < 512; off <<= 1) {
    int t = (tid >= off) ? tmp[tid - off] : 0;
    __syncthreads();
    if (tid >= off) tmp[tid] += t;
    __syncthreads();
  }
  if (tid < nb) bsum[tid] = tmp[tid] - v;
}

__global__ __launch_bounds__(256) void add_offsets(int* __restrict__ cnt,
                                                   const int* __restrict__ bsum,
                                                   int* __restrict__ row_ptr) {
  int i = blockIdx.x * 256 + threadIdx.x;
  if (i < N_NODES) {
    int r = cnt[i] + bsum[blockIdx.x];
    row_ptr[i] = r;
    cnt[i] = r;
  }
  if (i == 0) row_ptr[N_NODES] = N_EDGES;
}

__global__ __launch_bounds__(256) void csr_fill(const int* __restrict__ ei,
                                                const float* __restrict__ ew,
                                                int* __restrict__ cursor,
                                                int2* __restrict__ edges) {
  int e = blockIdx.x * 256 + threadIdx.x;
  if (e < N_EDGES) {
    int d = ei[e + N_EDGES];
    int p = atomicAdd(&cursor[d], 1);
    edges[p] = make_int2(ei[e], __float_as_int(ew[e]));
  }
}

// ---------------- gather aggregation + (optional) fused BN stats + dropout mask
// HALF-WAVE per node: 32 lanes x uint2 (4 channels each); 8 nodes per 256-thr block.
// STATS: also generates the NEXT layer's dropout mask (threefry hidden under
// the gather's memory stalls); nibble-pack via LDS. mask[node*4+q] bit b = keep(32q+b).
template <bool STATS>
__global__ __launch_bounds__(256) void gather_agg(const unsigned int* __restrict__ Hb,
                                                  const int* __restrict__ row_ptr,
                                                  const int2* __restrict__ edges,
                                                  const float* __restrict__ bias,
                                                  float* __restrict__ AGG,
                                                  float* __restrict__ partials,
                                                  unsigned int* __restrict__ mask,
                                                  uint32_t mk0, uint32_t mk1) {
  const int hw = threadIdx.x >> 5;          // 0..7 half-wave slot
  const int l32 = threadIdx.x & 31;         // lane within half-wave
  const int node = blockIdx.x * 8 + hw;
  float4 acc = *(const float4*)(bias + l32 * 4);
  const int beg = row_ptr[node];
  const int end = row_ptr[node + 1];
  const unsigned int* Hp = Hb + l32 * 2;
  int j = beg;
  for (; j + 3 < end; j += 4) {
    int2 e0 = edges[j + 0];
    int2 e1 = edges[j + 1];
    int2 e2 = edges[j + 2];
    int2 e3 = edges[j + 3];
    uint2 u0 = *(const uint2*)(Hp + (size_t)e0.x * 64);
    uint2 u1 = *(const uint2*)(Hp + (size_t)e1.x * 64);
    uint2 u2 = *(const uint2*)(Hp + (size_t)e2.x * 64);
    uint2 u3 = *(const uint2*)(Hp + (size_t)e3.x * 64);
    float w0 = __int_as_float(e0.y), w1 = __int_as_float(e1.y);
    float w2 = __int_as_float(e2.y), w3 = __int_as_float(e3.y);
    acc.x += w0 * bf_lo(u0.x) + w1 * bf_lo(u1.x) + w2 * bf_lo(u2.x) + w3 * bf_lo(u3.x);
    acc.y += w0 * bf_hi(u0.x) + w1 * bf_hi(u1.x) + w2 * bf_hi(u2.x) + w3 * bf_hi(u3.x);
    acc.z += w0 * bf_lo(u0.y) + w1 * bf_lo(u1.y) + w2 * bf_lo(u2.y) + w3 * bf_lo(u3.y);
    acc.w += w0 * bf_hi(u0.y) + w1 * bf_hi(u1.y) + w2 * bf_hi(u2.y) + w3 * bf_hi(u3.y);
  }
  for (; j < end; ++j) {
    int2 e = edges[j];
    uint2 u = *(const uint2*)(Hp + (size_t)e.x * 64);
    float w = __int_as_float(e.y);
    acc.x += w * bf_lo(u.x);
    acc.y += w * bf_hi(u.x);
    acc.z += w * bf_lo(u.y);
    acc.w += w * bf_hi(u.y);
  }
  *(float4*)(AGG + (size_t)node * 128 + l32 * 4) = acc;

  if (STATS) {
    // dropout keep-bits for this node's 4 channels
    uint32_t ibase = (uint32_t)(node * 128 + l32 * 4);
    uint32_t v = 0;
#pragma unroll
    for (int jj = 0; jj < 4; ++jj) {
      uint32_t bits = jax_bits32(mk0, mk1, ibase + jj);
      v |= (uint32_t)(!(bits >> 31)) << jj;
    }
    __shared__ uint32_t nib[8][32];
    __shared__ float st[8][256];
    nib[hw][l32] = v;
    st[hw][l32 * 4 + 0] = acc.x;
    st[hw][l32 * 4 + 1] = acc.y;
    st[hw][l32 * 4 + 2] = acc.z;
    st[hw][l32 * 4 + 3] = acc.w;
    st[hw][128 + l32 * 4 + 0] = acc.x * acc.x;
    st[hw][128 + l32 * 4 + 1] = acc.y * acc.y;
    st[hw][128 + l32 * 4 + 2] = acc.z * acc.z;
    st[hw][128 + l32 * 4 + 3] = acc.w * acc.w;
    __syncthreads();
    float t = 0.f;
#pragma unroll
    for (int g = 0; g < 8; ++g) t += st[g][threadIdx.x];
    unsafeAtomicAdd(&partials[(blockIdx.x & 63) * 256 + threadIdx.x], t);
    if (l32 < 4) {
      int q = l32;
      uint32_t w = 0;
#pragma unroll
      for (int i = 0; i < 8; ++i) w |= nib[hw][8 * q + i] << (4 * i);
      mask[node * 4 + q] = w;
    }
  }
}

// read 64x256 partials -> ss; re-zero partials for the next layer
__global__ __launch_bounds__(128) void stats_finalize(float* __restrict__ partials,
                                                      const float* __restrict__ g,
                                                      const float* __restrict__ bt,
                                                      float2* __restrict__ ss) {
  int c = threadIdx.x;
  float s = 0.f, q = 0.f;
#pragma unroll 8
  for (int b = 0; b < 64; ++b) {
    s += partials[b * 256 + c];
    q += partials[b * 256 + 128 + c];
  }
#pragma unroll 8
  for (int b = 0; b < 64; ++b) {
    partials[b * 256 + c] = 0.f;
    partials[b * 256 + 128 + c] = 0.f;
  }
  float mu = s * (1.0f / N_NODES);
  float var = fmaxf(q * (1.0f / N_NODES) - mu * mu, 0.f);
  float inv = rsqrtf(var + BN_EPS);
  float sc = g[c] * inv;
  ss[c] = make_float2(sc, bt[c] - mu * sc);
}

// ---------------- jk_final via MFMA (LDS version): jk = max(bf16 X1, bf16 X2, fp32 X3);
// OUT = log_softmax(jk @ Wf + bf). 64 rows/block; A=jk bf16, B=Wf^T bf16 in LDS.
__global__ __launch_bounds__(256) void jk_final_mfma(const unsigned int* __restrict__ X1b,
                                                     const unsigned int* __restrict__ X2b,
                                                     const float* __restrict__ X3,
                                                     const float* __restrict__ Wf,
                                                     const float* __restrict__ bf,
                                                     float* __restrict__ OUT) {
  __shared__ __align__(16) unsigned short Wt[64 * LP];   // Wt[col][k]
  __shared__ __align__(16) unsigned short At[64 * LP];   // jk rows bf16
  const int tid = threadIdx.x;
  const int rbase = blockIdx.x * 64;
#pragma unroll
  for (int i = 0; i < 8; ++i) {             // 2048 float4 = 128 k x 16 cq
    int f4 = tid + i * 256;
    int k = f4 >> 4;
    int cq = f4 & 15;
    float4 w = *(const float4*)(Wf + k * 64 + cq * 4);
    Wt[(cq * 4 + 0) * LP + k] = f2bf(w.x);
    Wt[(cq * 4 + 1) * LP + k] = f2bf(w.y);
    Wt[(cq * 4 + 2) * LP + k] = f2bf(w.z);
    Wt[(cq * 4 + 3) * LP + k] = f2bf(w.w);
  }
#pragma unroll
  for (int i = 0; i < 8; ++i) {             // 2048 quads = 64 r x 32 cq
    int f4 = tid + i * 256;
    int r = f4 >> 5;
    int cq = f4 & 31;
    int grow = rbase + r;
    if (grow >= N_NODES) grow = N_NODES - 1;
    uint2 u1 = *(const uint2*)(X1b + (size_t)grow * 64 + cq * 2);
    uint2 u2 = *(const uint2*)(X2b + (size_t)grow * 64 + cq * 2);
    float4 x3 = *(const float4*)(X3 + (size_t)grow * 128 + cq * 4);
    float m0 = fmaxf(fmaxf(bf_lo(u1.x), bf_lo(u2.x)), x3.x);
    float m1 = fmaxf(fmaxf(bf_hi(u1.x), bf_hi(u2.x)), x3.y);
    float m2 = fmaxf(fmaxf(bf_lo(u1.y), bf_lo(u2.y)), x3.z);
    float m3 = fmaxf(fmaxf(bf_hi(u1.y), bf_hi(u2.y)), x3.w);
    uint32_t p0 = (uint32_t)f2bf(m0) | ((uint32_t)f2bf(m1) << 16);
    uint32_t p1 = (uint32_t)f2bf(m2) | ((uint32_t)f2bf(m3) << 16);
    *(uint2*)(At + r * LP + cq * 4) = make_uint2(p0, p1);
  }
  __syncthreads();
  const int lane = tid & 63;
  const int wv = tid >> 6;
  const int m = lane & 15;
  const int kg = lane >> 4;
  f32x4 acc0 = {0,0,0,0}, acc1 = {0,0,0,0}, acc2 = {0,0,0,0}, acc3 = {0,0,0,0};
  const unsigned short* Arow = At + (wv * 16 + m) * LP;
#pragma unroll
  for (int ks = 0; ks < 4; ++ks) {
    bf16x8 af = *(const bf16x8*)(Arow + ks * 32 + kg * 8);
#define MF(n, accn) { bf16x8 bfr = *(const bf16x8*)(Wt + (n * 16 + m) * LP + ks * 32 + kg * 8); \
    accn = __builtin_amdgcn_mfma_f32_16x16x32_bf16(af, bfr, accn, 0, 0, 0); }
    MF(0, acc0) MF(1, acc1) MF(2, acc2) MF(3, acc3)
#undef MF
  }
  float bf0 = bf[m], bf1 = bf[16 + m], bf2 = bf[32 + m], bf3 = bf[48 + m];
#pragma unroll
  for (int j = 0; j < 4; ++j) {
    int row = rbase + wv * 16 + kg * 4 + j;
    float v0 = acc0[j] + bf0;
    float v1 = acc1[j] + bf1;
    float v2 = acc2[j] + bf2;
    float v3 = acc3[j] + bf3;
    float M = fmaxf(fmaxf(v0, v1), fmaxf(v2, v3));
#pragma unroll
    for (int s = 1; s < 16; s <<= 1) M = fmaxf(M, __shfl_xor(M, s));
    float sum = expf(v0 - M) + expf(v1 - M) + expf(v2 - M) + expf(v3 - M);
#pragma unroll
    for (int s = 1; s < 16; s <<= 1) sum += __shfl_xor(sum, s);
    float ls = M + logf(sum);
    if (row < N_NODES) {
      float* o = OUT + (size_t)row * 64;
      o[m] = v0 - ls;
      o[16 + m] = v1 - ls;
      o[32 + m] = v2 - ls;
      o[48 + m] = v3 - ls;
    }
  }
}

extern "C" void kernel_launch(void* const* d_in, const int* in_sizes, int n_in,
                              void* d_out, int out_size, void* d_ws, size_t ws_size,
                              hipStream_t stream) {
  const float* x   = (const float*)d_in[0];
  const int*   ei  = (const int*)d_in[1];
  const float* ew  = (const float*)d_in[2];
  const float* W1  = (const float*)d_in[3];
  const float* b1  = (const float*)d_in[4];
  const float* W2  = (const float*)d_in[5];
  const float* b2  = (const float*)d_in[6];
  const float* W3  = (const float*)d_in[7];
  const float* b3  = (const float*)d_in[8];
  const float* g1  = (const float*)d_in[9];
  const float* bt1 = (const float*)d_in[10];
  const float* g2  = (const float*)d_in[11];
  const float* bt2 = (const float*)d_in[12];
  const float* Wf  = (const float*)d_in[13];
  const float* bfb = (const float*)d_in[14];
  float* out = (float*)d_out;

  float* B0 = (float*)d_ws;                // P buffer (bf16 ushort[NELEMS])
  float* B1 = B0 + NELEMS;                 // AGG fp32
  float* B2 = B1 + NELEMS;                 // X1 bf16 (uses half)
  float* B3 = B2 + NELEMS;                 // X2 bf16 (uses half)
  int2* edges = (int2*)(B3 + NELEMS);      // N_EDGES int2
  int* cursor = (int*)(edges + N_EDGES);   // N_NODES
  int* row_ptr = cursor + N_NODES;         // N_NODES+1
  int* bsum = row_ptr + N_NODES + 1;       // 512
  float* partials = (float*)(bsum + 512);  // 64*256 floats (64KB)
  float2* ss1 = (float2*)(partials + 64 * 256);    // 128 float2
  float2* ss2 = ss1 + 128;
  unsigned short* Wt2 = (unsigned short*)(ss2 + 128);  // 128*128 bf16
  unsigned short* Wt3 = Wt2 + 128 * 128;
  unsigned int* mask1 = (unsigned int*)(Wt3 + 128 * 128);  // N_NODES*4 u32
  unsigned int* mask2 = mask1 + N_NODES * 4;
  unsigned short* P = (unsigned short*)B0;
  unsigned int* Pu = (unsigned int*)B0;
  unsigned int* X1b = (unsigned int*)B2;
  unsigned int* X2b = (unsigned int*)B3;

  // JAX partitionable split of key(42)=(0,42): k_i = threefry(key, (0,i)) full pair
  uint32_t k1_0, k1_1, k2_0, k2_1;
  threefry2x32(0u, 42u, 0u, 0u, k1_0, k1_1);
  threefry2x32(0u, 42u, 0u, 1u, k2_0, k2_1);

  const int GEMM_GRID = (N_NODES + 63) / 64;       // 1563
  const int EDGE_GRID = (N_EDGES + 255) / 256;     // 2344
  const int NODE_GRID = (N_NODES + 255) / 256;     // 391
  const int AGG_GRID  = N_NODES / 8;               // 12500 (half-wave per node)
  const int FINAL_GRID = (N_NODES + 63) / 64;      // 1563
  const int TR_GRID = (2 * 128 * 128 + 255) / 256; // 128

  // ---- W2/W3 pre-transpose + CSR build + zero partials
  transpose_w23<<<TR_GRID, 256, 0, stream>>>(W2, W3, Wt2, Wt3);
  hipMemsetAsync(cursor, 0, N_NODES * sizeof(int), stream);
  hipMemsetAsync(partials, 0, 64 * 256 * sizeof(float), stream);
  csr_count<<<EDGE_GRID, 256, 0, stream>>>(ei, cursor);
  scan_blocks<<<NODE_GRID, 256, 0, stream>>>(cursor, bsum);
  scan_bsum<<<1, 512, 0, stream>>>(bsum, NODE_GRID);
  add_offsets<<<NODE_GRID, 256, 0, stream>>>(cursor, bsum, row_ptr);
  csr_fill<<<EDGE_GRID, 256, 0, stream>>>(ei, ew, cursor, edges);

  // ---- layer 1: P = bf16(x@W1) ; AGG1 = gather(P)+b1 (+stats +mask1) ; ss1
  gemm_mfma<<<GEMM_GRID, 256, 0, stream>>>(x, W1, P);
  gather_agg<true><<<AGG_GRID, 256, 0, stream>>>(Pu, row_ptr, edges, b1, B1, partials,
                                                 mask1, k1_0, k1_1);
  stats_finalize<<<1, 128, 0, stream>>>(partials, g1, bt1, ss1);
  // ---- layer 2: fused BN1+ReLU (-> X1 bf16) + mask1-dropout + MFMA GEMM W2 -> P
  gemm_mfma_fused<<<GEMM_GRID, 256, 0, stream>>>(B1, ss1, Wt2, mask1, X1b, P);
  gather_agg<true><<<AGG_GRID, 256, 0, stream>>>(Pu, row_ptr, edges, b2, B1, partials,
                                                 mask2, k2_0, k2_1);
  stats_finalize<<<1, 128, 0, stream>>>(partials, g2, bt2, ss2);
  // ---- layer 3: fused BN2+ReLU (-> X2 bf16) + mask2-dropout + MFMA GEMM W3 -> P
  gemm_mfma_fused<<<GEMM_GRID, 256, 0, stream>>>(B1, ss2, Wt3, mask2, X2b, P);
  gather_agg<false><<<AGG_GRID, 256, 0, stream>>>(Pu, row_ptr, edges, b3, B1, nullptr,
                                                  nullptr, 0u, 0u);
  // ---- JK max + final linear + log_softmax (MFMA)
  jk_final_mfma<<<FINAL_GRID, 256, 0, stream>>>(X1b, X2b, B1, Wf, bfb, out);
}

// Round 23
// 339.983 us; speedup vs baseline: 1.1491x; 1.0629x over previous
//
#include <hip/hip_runtime.h>
#include <stdint.h>

#define N_NODES 100000
#define N_EDGES 600000
#define HID 128
#define OUT_C 64
#define NELEMS 12800000      // 100000*128
#define BN_EPS 1e-5f
#define LP 136               // LDS row pitch in bf16 elems

typedef short bf16x8 __attribute__((ext_vector_type(8)));
typedef float f32x4 __attribute__((ext_vector_type(4)));

__device__ __forceinline__ unsigned short f2bf(float f) {   // RNE float->bf16
  uint32_t u = __float_as_uint(f);
  uint32_t r = u + 0x7FFFu + ((u >> 16) & 1u);
  return (unsigned short)(r >> 16);
}
__device__ __forceinline__ float bf_lo(uint32_t u) { return __uint_as_float(u << 16); }
__device__ __forceinline__ float bf_hi(uint32_t u) { return __uint_as_float(u & 0xFFFF0000u); }

// ---------------- threefry2x32 (matches JAX) ----------------
__device__ __host__ __forceinline__ void threefry2x32(uint32_t k0, uint32_t k1,
                                                      uint32_t x0, uint32_t x1,
                                                      uint32_t& o0, uint32_t& o1) {
  uint32_t ks0 = k0, ks1 = k1, ks2 = k0 ^ k1 ^ 0x1BD11BDAu;
  x0 += ks0; x1 += ks1;
#define TFR(r) { x0 += x1; x1 = (x1 << (r)) | (x1 >> (32 - (r))); x1 ^= x0; }
  TFR(13) TFR(15) TFR(26) TFR(6)
  x0 += ks1; x1 += ks2 + 1u;
  TFR(17) TFR(29) TFR(16) TFR(24)
  x0 += ks2; x1 += ks0 + 2u;
  TFR(13) TFR(15) TFR(26) TFR(6)
  x0 += ks0; x1 += ks1 + 3u;
  TFR(17) TFR(29) TFR(16) TFR(24)
  x0 += ks1; x1 += ks2 + 4u;
  TFR(13) TFR(15) TFR(26) TFR(6)
  x0 += ks2; x1 += ks0 + 5u;
#undef TFR
  o0 = x0; o1 = x1;
}

__device__ __forceinline__ uint32_t jax_bits32(uint32_t k0, uint32_t k1, uint32_t i) {
  uint32_t b0, b1;
  threefry2x32(k0, k1, 0u, i, b0, b1);
  return b0 ^ b1;
}

// ---------------- one-time W transpose+cast for W2+W3 in one launch ----------------
__global__ __launch_bounds__(256) void transpose_w23(const float* __restrict__ W2,
                                                     const float* __restrict__ W3,
                                                     unsigned short* __restrict__ Wt2,
                                                     unsigned short* __restrict__ Wt3) {
  int idx = blockIdx.x * 256 + threadIdx.x;        // 0 .. 2*16384
  const float* W = (idx < 16384) ? W2 : W3;
  unsigned short* out = (idx < 16384) ? Wt2 : Wt3;
  int e = idx & 16383;
  int k = e >> 7, c = e & 127;
  out[c * 128 + k] = f2bf(W[e]);
}

// ---------------- MFMA GEMM core (LDS-staged, layer-1 + jk) ----------------
__device__ __forceinline__ void stage_Wt(const float* __restrict__ W,
                                         unsigned short* Wt, int tid) {
#pragma unroll
  for (int i = 0; i < 16; ++i) {            // 4096 float4 = 128 k x 32 cq
    int f4 = tid + i * 256;
    int k = f4 >> 5;
    int cq = f4 & 31;
    float4 w = *(const float4*)(W + k * 128 + cq * 4);
    Wt[(cq * 4 + 0) * LP + k] = f2bf(w.x);
    Wt[(cq * 4 + 1) * LP + k] = f2bf(w.y);
    Wt[(cq * 4 + 2) * LP + k] = f2bf(w.z);
    Wt[(cq * 4 + 3) * LP + k] = f2bf(w.w);
  }
}

__device__ __forceinline__ void mfma_compute_store(const unsigned short* At,
                                                   const unsigned short* Wt,
                                                   unsigned short* __restrict__ O,
                                                   int rbase, int tid) {
  const int lane = tid & 63;
  const int wv = tid >> 6;
  const int m = lane & 15;
  const int kg = lane >> 4;
  f32x4 acc0 = {0,0,0,0}, acc1 = {0,0,0,0}, acc2 = {0,0,0,0}, acc3 = {0,0,0,0};
  f32x4 acc4 = {0,0,0,0}, acc5 = {0,0,0,0}, acc6 = {0,0,0,0}, acc7 = {0,0,0,0};
  const unsigned short* Arow = At + (wv * 16 + m) * LP;
#pragma unroll
  for (int ks = 0; ks < 4; ++ks) {
    bf16x8 af = *(const bf16x8*)(Arow + ks * 32 + kg * 8);
#define MF(n, accn) { bf16x8 bfr = *(const bf16x8*)(Wt + (n * 16 + m) * LP + ks * 32 + kg * 8); \
    accn = __builtin_amdgcn_mfma_f32_16x16x32_bf16(af, bfr, accn, 0, 0, 0); }
    MF(0, acc0) MF(1, acc1) MF(2, acc2) MF(3, acc3)
    MF(4, acc4) MF(5, acc5) MF(6, acc6) MF(7, acc7)
#undef MF
  }
#define ST(n, accn) {                                                       \
  _Pragma("unroll")                                                         \
  for (int j = 0; j < 4; ++j) {                                             \
    int grow = rbase + wv * 16 + kg * 4 + j;                                \
    if (grow < N_NODES) O[(size_t)grow * 128 + n * 16 + m] = f2bf(accn[j]); \
  } }
  ST(0, acc0) ST(1, acc1) ST(2, acc2) ST(3, acc3)
  ST(4, acc4) ST(5, acc5) ST(6, acc6) ST(7, acc7)
#undef ST
}

// plain (layer 1): O = bf16(A) @ bf16(W), O stored bf16
__global__ __launch_bounds__(256) void gemm_mfma(const float* __restrict__ A,
                                                 const float* __restrict__ W,
                                                 unsigned short* __restrict__ O) {
  __shared__ __align__(16) unsigned short Wt[128 * LP];
  __shared__ __align__(16) unsigned short At[64 * LP];
  const int tid = threadIdx.x;
  const int rbase = blockIdx.x * 64;
  stage_Wt(W, Wt, tid);
#pragma unroll
  for (int i = 0; i < 8; ++i) {             // 2048 float4 = 64 r x 32 cq
    int f4 = tid + i * 256;
    int r = f4 >> 5;
    int cq = f4 & 31;
    int grow = rbase + r;
    if (grow >= N_NODES) grow = N_NODES - 1;
    float4 a = *(const float4*)(A + (size_t)grow * 128 + cq * 4);
    uint32_t p0 = (uint32_t)f2bf(a.x) | ((uint32_t)f2bf(a.y) << 16);
    uint32_t p1 = (uint32_t)f2bf(a.z) | ((uint32_t)f2bf(a.w) << 16);
    *(uint2*)(At + r * LP + cq * 4) = make_uint2(p0, p1);
  }
  __syncthreads();
  mfma_compute_store(At, Wt, O, rbase, tid);
}

// fused (layers 2,3): LDS-FREE main body. Block prologue reduces the 64x256
// stats partials -> ss in LDS (removes the stats_finalize launch).
// BN(scale/shift)+ReLU -> Xb bf16; dropout (threefry, r20-best placement)
// -> bf16 A-fragments; B from pre-transposed global bf16 Wt[c][k] (pitch 128).
__global__ __launch_bounds__(256) void gemm_mfma_fused(const float* __restrict__ AGG,
                                                       const float* __restrict__ partials,
                                                       const float* __restrict__ g,
                                                       const float* __restrict__ bt,
                                                       const unsigned short* __restrict__ Wt,
                                                       unsigned int* __restrict__ Xb,
                                                       unsigned short* __restrict__ O,
                                                       uint32_t k0, uint32_t k1) {
  const int tid = threadIdx.x;
  __shared__ float red[256];
  __shared__ float2 ssl[128];
  {
    float t0 = 0.f;
#pragma unroll 8
    for (int b = 0; b < 64; ++b) t0 += partials[b * 256 + tid];
    red[tid] = t0;
    __syncthreads();
    if (tid < 128) {
      float s = red[tid], q = red[128 + tid];
      float mu = s * (1.0f / N_NODES);
      float var = fmaxf(q * (1.0f / N_NODES) - mu * mu, 0.f);
      float inv = rsqrtf(var + BN_EPS);
      float sc = g[tid] * inv;
      ssl[tid] = make_float2(sc, bt[tid] - mu * sc);
    }
    __syncthreads();
  }
  const int lane = tid & 63;
  const int wv = tid >> 6;
  const int m = lane & 15;
  const int kg = lane >> 4;
  const int rbase = blockIdx.x * 64;
  int row = rbase + wv * 16 + m;
  bool valid = row < N_NODES;
  int rowc = valid ? row : N_NODES - 1;
  const float* Ar = AGG + (size_t)rowc * 128 + kg * 8;
  bf16x8 af0, af1, af2, af3;
#define LDF(ksc, afk) {                                                        \
    float4 a0 = *(const float4*)(Ar + ksc);                                    \
    float4 a1 = *(const float4*)(Ar + ksc + 4);                                \
    const float2* ssp = ssl + ksc + kg * 8;                                    \
    float av[8] = {a0.x, a0.y, a0.z, a0.w, a1.x, a1.y, a1.z, a1.w};            \
    unsigned short yb[8];                                                      \
    _Pragma("unroll")                                                          \
    for (int jj = 0; jj < 8; ++jj) {                                           \
      float2 sv = ssp[jj];                                                     \
      float yv = fmaxf(fmaf(av[jj], sv.x, sv.y), 0.f);                         \
      uint32_t bits = jax_bits32(k0, k1, (uint32_t)(rowc * 128 + ksc + kg * 8 + jj)); \
      yb[jj] = f2bf(yv);                                                       \
      afk[jj] = (short)f2bf((bits & 0x80000000u) ? 0.f : 2.f * yv);            \
    }                                                                          \
    if (valid) {                                                               \
      uint4 yp;                                                                \
      yp.x = (uint32_t)yb[0] | ((uint32_t)yb[1] << 16);                        \
      yp.y = (uint32_t)yb[2] | ((uint32_t)yb[3] << 16);                        \
      yp.z = (uint32_t)yb[4] | ((uint32_t)yb[5] << 16);                        \
      yp.w = (uint32_t)yb[6] | ((uint32_t)yb[7] << 16);                        \
      *(uint4*)(Xb + (size_t)row * 64 + (ksc) / 2 + kg * 4) = yp;              \
    } }
  LDF(0, af0) LDF(32, af1) LDF(64, af2) LDF(96, af3)
#undef LDF
  f32x4 acc0 = {0,0,0,0}, acc1 = {0,0,0,0}, acc2 = {0,0,0,0}, acc3 = {0,0,0,0};
  f32x4 acc4 = {0,0,0,0}, acc5 = {0,0,0,0}, acc6 = {0,0,0,0}, acc7 = {0,0,0,0};
  const unsigned short* Wm = Wt + m * 128 + kg * 8;
#define MFMA_ALL(afk, ksc)                                                              \
  acc0 = __builtin_amdgcn_mfma_f32_16x16x32_bf16(afk, *(const bf16x8*)(Wm + 0 * 2048 + ksc), acc0, 0, 0, 0); \
  acc1 = __builtin_amdgcn_mfma_f32_16x16x32_bf16(afk, *(const bf16x8*)(Wm + 1 * 2048 + ksc), acc1, 0, 0, 0); \
  acc2 = __builtin_amdgcn_mfma_f32_16x16x32_bf16(afk, *(const bf16x8*)(Wm + 2 * 2048 + ksc), acc2, 0, 0, 0); \
  acc3 = __builtin_amdgcn_mfma_f32_16x16x32_bf16(afk, *(const bf16x8*)(Wm + 3 * 2048 + ksc), acc3, 0, 0, 0); \
  acc4 = __builtin_amdgcn_mfma_f32_16x16x32_bf16(afk, *(const bf16x8*)(Wm + 4 * 2048 + ksc), acc4, 0, 0, 0); \
  acc5 = __builtin_amdgcn_mfma_f32_16x16x32_bf16(afk, *(const bf16x8*)(Wm + 5 * 2048 + ksc), acc5, 0, 0, 0); \
  acc6 = __builtin_amdgcn_mfma_f32_16x16x32_bf16(afk, *(const bf16x8*)(Wm + 6 * 2048 + ksc), acc6, 0, 0, 0); \
  acc7 = __builtin_amdgcn_mfma_f32_16x16x32_bf16(afk, *(const bf16x8*)(Wm + 7 * 2048 + ksc), acc7, 0, 0, 0);
  MFMA_ALL(af0, 0) MFMA_ALL(af1, 32) MFMA_ALL(af2, 64) MFMA_ALL(af3, 96)
#undef MFMA_ALL
#pragma unroll
  for (int j = 0; j < 4; ++j) {
    int orow = rbase + wv * 16 + kg * 4 + j;
    if (orow < N_NODES) {
      unsigned short* op = O + (size_t)orow * 128 + m;
      op[0 * 16] = f2bf(acc0[j]); op[1 * 16] = f2bf(acc1[j]);
      op[2 * 16] = f2bf(acc2[j]); op[3 * 16] = f2bf(acc3[j]);
      op[4 * 16] = f2bf(acc4[j]); op[5 * 16] = f2bf(acc5[j]);
      op[6 * 16] = f2bf(acc6[j]); op[7 * 16] = f2bf(acc7[j]);
    }
  }
}

// ---------------- CSR build ----------------
__global__ __launch_bounds__(256) void csr_count(const int* __restrict__ ei,
                                                 int* __restrict__ cnt) {
  int e = blockIdx.x * 256 + threadIdx.x;
  if (e < N_EDGES) atomicAdd(&cnt[ei[e + N_EDGES]], 1);
}

__global__ __launch_bounds__(256) void scan_blocks(int* __restrict__ cnt,
                                                   int* __restrict__ bsum) {
  __shared__ int tmp[256];
  int tid = threadIdx.x;
  int i = blockIdx.x * 256 + tid;
  int v = (i < N_NODES) ? cnt[i] : 0;
  tmp[tid] = v;
  __syncthreads();
  for (int off = 1; off < 256; off <<= 1) {
    int t = (tid >= off) ? tmp[tid - off] : 0;
    __syncthreads();
    if (tid >= off) tmp[tid] += t;
    __syncthreads();
  }
  if (i < N_NODES) cnt[i] = tmp[tid] - v;
  if (tid == 255) bsum[blockIdx.x] = tmp[255];
}

__global__ __launch_bounds__(512) void scan_bsum(int* __restrict__ bsum, int nb) {
  __shared__ int tmp[512];
  int tid = threadIdx.x;
  int v = (tid < nb) ? bsum[tid] : 0;
  tmp[tid] = v;
  __syncthreads();
  for (int off = 1; off < 512; off <<= 1) {
    int t = (tid >= off) ? tmp[tid - off] : 0;
    __syncthreads();
    if (tid >= off) tmp[tid] += t;
    __syncthreads();
  }
  if (tid < nb) bsum[tid] = tmp[tid] - v;
}

__global__ __launch_bounds__(256) void add_offsets(int* __restrict__ cnt,
                                                   const int* __restrict__ bsum,
                                                   int* __restrict__ row_ptr) {
  int i = blockIdx.x * 256 + threadIdx.x;
  if (i < N_NODES) {
    int r = cnt[i] + bsum[blockIdx.x];
    row_ptr[i] = r;
    cnt[i] = r;
  }
  if (i == 0) row_ptr[N_NODES] = N_EDGES;
}

__global__ __launch_bounds__(256) void csr_fill(const int* __restrict__ ei,
                                                const float* __restrict__ ew,
                                                int* __restrict__ cursor,
                                                int2* __restrict__ edges) {
  int e = blockIdx.x * 256 + threadIdx.x;
  if (e < N_EDGES) {
    int d = ei[e + N_EDGES];
    int p = atomicAdd(&cursor[d], 1);
    edges[p] = make_int2(ei[e], __float_as_int(ew[e]));
  }
}

// ---------------- gather aggregation + (optional) fused BN stats
// HALF-WAVE per node: 32 lanes x uint2 (4 channels each); 8 nodes per 256-thr block.
// STATS: fp32 AGG + block LDS-reduce -> 64-bucket atomic partials (r20 form).
// !STATS (layer 3): AGG written bf16 (feeds only jk's max).
template <bool STATS>
__global__ __launch_bounds__(256) void gather_agg(const unsigned int* __restrict__ Hb,
                                                  const int* __restrict__ row_ptr,
                                                  const int2* __restrict__ edges,
                                                  const float* __restrict__ bias,
                                                  float* __restrict__ AGGf,
                                                  unsigned int* __restrict__ AGGb,
                                                  float* __restrict__ partials) {
  const int hw = threadIdx.x >> 5;          // 0..7 half-wave slot
  const int l32 = threadIdx.x & 31;         // lane within half-wave
  const int node = blockIdx.x * 8 + hw;
  float4 acc = *(const float4*)(bias + l32 * 4);
  const int beg = row_ptr[node];
  const int end = row_ptr[node + 1];
  const unsigned int* Hp = Hb + l32 * 2;
  int j = beg;
  for (; j + 3 < end; j += 4) {
    int2 e0 = edges[j + 0];
    int2 e1 = edges[j + 1];
    int2 e2 = edges[j + 2];
    int2 e3 = edges[j + 3];
    uint2 u0 = *(const uint2*)(Hp + (size_t)e0.x * 64);
    uint2 u1 = *(const uint2*)(Hp + (size_t)e1.x * 64);
    uint2 u2 = *(const uint2*)(Hp + (size_t)e2.x * 64);
    uint2 u3 = *(const uint2*)(Hp + (size_t)e3.x * 64);
    float w0 = __int_as_float(e0.y), w1 = __int_as_float(e1.y);
    float w2 = __int_as_float(e2.y), w3 = __int_as_float(e3.y);
    acc.x += w0 * bf_lo(u0.x) + w1 * bf_lo(u1.x) + w2 * bf_lo(u2.x) + w3 * bf_lo(u3.x);
    acc.y += w0 * bf_hi(u0.x) + w1 * bf_hi(u1.x) + w2 * bf_hi(u2.x) + w3 * bf_hi(u3.x);
    acc.z += w0 * bf_lo(u0.y) + w1 * bf_lo(u1.y) + w2 * bf_lo(u2.y) + w3 * bf_lo(u3.y);
    acc.w += w0 * bf_hi(u0.y) + w1 * bf_hi(u1.y) + w2 * bf_hi(u2.y) + w3 * bf_hi(u3.y);
  }
  for (; j < end; ++j) {
    int2 e = edges[j];
    uint2 u = *(const uint2*)(Hp + (size_t)e.x * 64);
    float w = __int_as_float(e.y);
    acc.x += w * bf_lo(u.x);
    acc.y += w * bf_hi(u.x);
    acc.z += w * bf_lo(u.y);
    acc.w += w * bf_hi(u.y);
  }
  if (STATS) {
    *(float4*)(AGGf + (size_t)node * 128 + l32 * 4) = acc;
    __shared__ float st[8][256];
    st[hw][l32 * 4 + 0] = acc.x;
    st[hw][l32 * 4 + 1] = acc.y;
    st[hw][l32 * 4 + 2] = acc.z;
    st[hw][l32 * 4 + 3] = acc.w;
    st[hw][128 + l32 * 4 + 0] = acc.x * acc.x;
    st[hw][128 + l32 * 4 + 1] = acc.y * acc.y;
    st[hw][128 + l32 * 4 + 2] = acc.z * acc.z;
    st[hw][128 + l32 * 4 + 3] = acc.w * acc.w;
    __syncthreads();
    float t = 0.f;
#pragma unroll
    for (int g = 0; g < 8; ++g) t += st[g][threadIdx.x];
    unsafeAtomicAdd(&partials[(blockIdx.x & 63) * 256 + threadIdx.x], t);
  } else {
    uint2 p;
    p.x = (uint32_t)f2bf(acc.x) | ((uint32_t)f2bf(acc.y) << 16);
    p.y = (uint32_t)f2bf(acc.z) | ((uint32_t)f2bf(acc.w) << 16);
    *(uint2*)(AGGb + (size_t)node * 64 + l32 * 2) = p;
  }
}

// ---------------- jk_final via MFMA: jk = max(bf16 X1, bf16 X2, bf16 X3);
// OUT = log_softmax(jk @ Wf + bf). 64 rows/block; A=jk bf16, B=Wf^T bf16 in LDS.
__global__ __launch_bounds__(256) void jk_final_mfma(const unsigned int* __restrict__ X1b,
                                                     const unsigned int* __restrict__ X2b,
                                                     const unsigned int* __restrict__ X3b,
                                                     const float* __restrict__ Wf,
                                                     const float* __restrict__ bf,
                                                     float* __restrict__ OUT) {
  __shared__ __align__(16) unsigned short Wt[64 * LP];   // Wt[col][k]
  __shared__ __align__(16) unsigned short At[64 * LP];   // jk rows bf16
  const int tid = threadIdx.x;
  const int rbase = blockIdx.x * 64;
#pragma unroll
  for (int i = 0; i < 8; ++i) {             // 2048 float4 = 128 k x 16 cq
    int f4 = tid + i * 256;
    int k = f4 >> 4;
    int cq = f4 & 15;
    float4 w = *(const float4*)(Wf + k * 64 + cq * 4);
    Wt[(cq * 4 + 0) * LP + k] = f2bf(w.x);
    Wt[(cq * 4 + 1) * LP + k] = f2bf(w.y);
    Wt[(cq * 4 + 2) * LP + k] = f2bf(w.z);
    Wt[(cq * 4 + 3) * LP + k] = f2bf(w.w);
  }
#pragma unroll
  for (int i = 0; i < 8; ++i) {             // 2048 quads = 64 r x 32 cq
    int f4 = tid + i * 256;
    int r = f4 >> 5;
    int cq = f4 & 31;
    int grow = rbase + r;
    if (grow >= N_NODES) grow = N_NODES - 1;
    uint2 u1 = *(const uint2*)(X1b + (size_t)grow * 64 + cq * 2);
    uint2 u2 = *(const uint2*)(X2b + (size_t)grow * 64 + cq * 2);
    uint2 u3 = *(const uint2*)(X3b + (size_t)grow * 64 + cq * 2);
    float m0 = fmaxf(fmaxf(bf_lo(u1.x), bf_lo(u2.x)), bf_lo(u3.x));
    float m1 = fmaxf(fmaxf(bf_hi(u1.x), bf_hi(u2.x)), bf_hi(u3.x));
    float m2 = fmaxf(fmaxf(bf_lo(u1.y), bf_lo(u2.y)), bf_lo(u3.y));
    float m3 = fmaxf(fmaxf(bf_hi(u1.y), bf_hi(u2.y)), bf_hi(u3.y));
    uint32_t p0 = (uint32_t)f2bf(m0) | ((uint32_t)f2bf(m1) << 16);
    uint32_t p1 = (uint32_t)f2bf(m2) | ((uint32_t)f2bf(m3) << 16);
    *(uint2*)(At + r * LP + cq * 4) = make_uint2(p0, p1);
  }
  __syncthreads();
  const int lane = tid & 63;
  const int wv = tid >> 6;
  const int m = lane & 15;
  const int kg = lane >> 4;
  f32x4 acc0 = {0,0,0,0}, acc1 = {0,0,0,0}, acc2 = {0,0,0,0}, acc3 = {0,0,0,0};
  const unsigned short* Arow = At + (wv * 16 + m) * LP;
#pragma unroll
  for (int ks = 0; ks < 4; ++ks) {
    bf16x8 af = *(const bf16x8*)(Arow + ks * 32 + kg * 8);
#define MF(n, accn) { bf16x8 bfr = *(const bf16x8*)(Wt + (n * 16 + m) * LP + ks * 32 + kg * 8); \
    accn = __builtin_amdgcn_mfma_f32_16x16x32_bf16(af, bfr, accn, 0, 0, 0); }
    MF(0, acc0) MF(1, acc1) MF(2, acc2) MF(3, acc3)
#undef MF
  }
  float bf0 = bf[m], bf1 = bf[16 + m], bf2 = bf[32 + m], bf3 = bf[48 + m];
#pragma unroll
  for (int j = 0; j < 4; ++j) {
    int row = rbase + wv * 16 + kg * 4 + j;
    float v0 = acc0[j] + bf0;
    float v1 = acc1[j] + bf1;
    float v2 = acc2[j] + bf2;
    float v3 = acc3[j] + bf3;
    float M = fmaxf(fmaxf(v0, v1), fmaxf(v2, v3));
#pragma unroll
    for (int s = 1; s < 16; s <<= 1) M = fmaxf(M, __shfl_xor(M, s));
    float sum = expf(v0 - M) + expf(v1 - M) + expf(v2 - M) + expf(v3 - M);
#pragma unroll
    for (int s = 1; s < 16; s <<= 1) sum += __shfl_xor(sum, s);
    float ls = M + logf(sum);
    if (row < N_NODES) {
      float* o = OUT + (size_t)row * 64;
      o[m] = v0 - ls;
      o[16 + m] = v1 - ls;
      o[32 + m] = v2 - ls;
      o[48 + m] = v3 - ls;
    }
  }
}

extern "C" void kernel_launch(void* const* d_in, const int* in_sizes, int n_in,
                              void* d_out, int out_size, void* d_ws, size_t ws_size,
                              hipStream_t stream) {
  const float* x   = (const float*)d_in[0];
  const int*   ei  = (const int*)d_in[1];
  const float* ew  = (const float*)d_in[2];
  const float* W1  = (const float*)d_in[3];
  const float* b1  = (const float*)d_in[4];
  const float* W2  = (const float*)d_in[5];
  const float* b2  = (const float*)d_in[6];
  const float* W3  = (const float*)d_in[7];
  const float* b3  = (const float*)d_in[8];
  const float* g1  = (const float*)d_in[9];
  const float* bt1 = (const float*)d_in[10];
  const float* g2  = (const float*)d_in[11];
  const float* bt2 = (const float*)d_in[12];
  const float* Wf  = (const float*)d_in[13];
  const float* bfb = (const float*)d_in[14];
  float* out = (float*)d_out;

  float* B0 = (float*)d_ws;                // P buffer (bf16 ushort[NELEMS])
  float* B1 = B0 + NELEMS;                 // AGG fp32 (layers 1,2) / bf16 (layer 3)
  float* B2 = B1 + NELEMS;                 // X1 bf16 (uses half)
  float* B3 = B2 + NELEMS;                 // X2 bf16 (uses half)
  int2* edges = (int2*)(B3 + NELEMS);      // N_EDGES int2
  int* cursor = (int*)(edges + N_EDGES);   // N_NODES  (contiguous with partials for 1 memset)
  float* part1 = (float*)(cursor + N_NODES);   // 64*256 floats
  float* part2 = part1 + 64 * 256;             // 64*256 floats
  int* row_ptr = (int*)(part2 + 64 * 256);     // N_NODES+1
  int* bsum = row_ptr + N_NODES + 1;           // 512
  unsigned short* Wt2 = (unsigned short*)(bsum + 512);  // 128*128 bf16
  unsigned short* Wt3 = Wt2 + 128 * 128;
  unsigned short* P = (unsigned short*)B0;
  unsigned int* Pu = (unsigned int*)B0;
  unsigned int* X1b = (unsigned int*)B2;
  unsigned int* X2b = (unsigned int*)B3;
  unsigned int* AGG3b = (unsigned int*)B1;

  // JAX partitionable split of key(42)=(0,42): k_i = threefry(key, (0,i)) full pair
  uint32_t k1_0, k1_1, k2_0, k2_1;
  threefry2x32(0u, 42u, 0u, 0u, k1_0, k1_1);
  threefry2x32(0u, 42u, 0u, 1u, k2_0, k2_1);

  const int GEMM_GRID = (N_NODES + 63) / 64;       // 1563
  const int EDGE_GRID = (N_EDGES + 255) / 256;     // 2344
  const int NODE_GRID = (N_NODES + 255) / 256;     // 391
  const int AGG_GRID  = N_NODES / 8;               // 12500 (half-wave per node)
  const int FINAL_GRID = (N_NODES + 63) / 64;      // 1563
  const int TR_GRID = (2 * 128 * 128 + 255) / 256; // 128

  // ---- W2/W3 pre-transpose + CSR build + zero cursor+partials (one memset)
  transpose_w23<<<TR_GRID, 256, 0, stream>>>(W2, W3, Wt2, Wt3);
  hipMemsetAsync(cursor, 0, N_NODES * sizeof(int) + 2 * 64 * 256 * sizeof(float), stream);
  csr_count<<<EDGE_GRID, 256, 0, stream>>>(ei, cursor);
  scan_blocks<<<NODE_GRID, 256, 0, stream>>>(cursor, bsum);
  scan_bsum<<<1, 512, 0, stream>>>(bsum, NODE_GRID);
  add_offsets<<<NODE_GRID, 256, 0, stream>>>(cursor, bsum, row_ptr);
  csr_fill<<<EDGE_GRID, 256, 0, stream>>>(ei, ew, cursor, edges);

  // ---- layer 1: P = bf16(x@W1) ; AGG1 = gather(P)+b1 (+stats -> part1)
  gemm_mfma<<<GEMM_GRID, 256, 0, stream>>>(x, W1, P);
  gather_agg<true><<<AGG_GRID, 256, 0, stream>>>(Pu, row_ptr, edges, b1, B1, nullptr, part1);
  // ---- layer 2: fused [ss from part1] BN1+ReLU (-> X1 bf16) + dropout(k1) + GEMM W2 -> P
  gemm_mfma_fused<<<GEMM_GRID, 256, 0, stream>>>(B1, part1, g1, bt1, Wt2, X1b, P, k1_0, k1_1);
  gather_agg<true><<<AGG_GRID, 256, 0, stream>>>(Pu, row_ptr, edges, b2, B1, nullptr, part2);
  // ---- layer 3: fused [ss from part2] BN2+ReLU (-> X2 bf16) + dropout(k2) + GEMM W3 -> P
  gemm_mfma_fused<<<GEMM_GRID, 256, 0, stream>>>(B1, part2, g2, bt2, Wt3, X2b, P, k2_0, k2_1);
  gather_agg<false><<<AGG_GRID, 256, 0, stream>>>(Pu, row_ptr, edges, b3, nullptr, AGG3b, nullptr);
  // ---- JK max + final linear + log_softmax (MFMA, all-bf16 inputs)
  jk_final_mfma<<<FINAL_GRID, 256, 0, stream>>>(X1b, X2b, AGG3b, Wf, bfb, out);
}

// Round 24
// 332.813 us; speedup vs baseline: 1.1739x; 1.0215x over previous
//
#include <hip/hip_runtime.h>
#include <stdint.h>

#define N_NODES 100000
#define N_EDGES 600000
#define HID 128
#define OUT_C 64
#define NELEMS 12800000      // 100000*128
#define BN_EPS 1e-5f
#define LP 136               // LDS row pitch in bf16 elems
#define NBUCK 16             // stats partial buckets

typedef short bf16x8 __attribute__((ext_vector_type(8)));
typedef float f32x4 __attribute__((ext_vector_type(4)));

__device__ __forceinline__ unsigned short f2bf(float f) {   // RNE float->bf16
  uint32_t u = __float_as_uint(f);
  uint32_t r = u + 0x7FFFu + ((u >> 16) & 1u);
  return (unsigned short)(r >> 16);
}
__device__ __forceinline__ float bf_lo(uint32_t u) { return __uint_as_float(u << 16); }
__device__ __forceinline__ float bf_hi(uint32_t u) { return __uint_as_float(u & 0xFFFF0000u); }

// ---------------- threefry2x32 (matches JAX) ----------------
__device__ __host__ __forceinline__ void threefry2x32(uint32_t k0, uint32_t k1,
                                                      uint32_t x0, uint32_t x1,
                                                      uint32_t& o0, uint32_t& o1) {
  uint32_t ks0 = k0, ks1 = k1, ks2 = k0 ^ k1 ^ 0x1BD11BDAu;
  x0 += ks0; x1 += ks1;
#define TFR(r) { x0 += x1; x1 = (x1 << (r)) | (x1 >> (32 - (r))); x1 ^= x0; }
  TFR(13) TFR(15) TFR(26) TFR(6)
  x0 += ks1; x1 += ks2 + 1u;
  TFR(17) TFR(29) TFR(16) TFR(24)
  x0 += ks2; x1 += ks0 + 2u;
  TFR(13) TFR(15) TFR(26) TFR(6)
  x0 += ks0; x1 += ks1 + 3u;
  TFR(17) TFR(29) TFR(16) TFR(24)
  x0 += ks1; x1 += ks2 + 4u;
  TFR(13) TFR(15) TFR(26) TFR(6)
  x0 += ks2; x1 += ks0 + 5u;
#undef TFR
  o0 = x0; o1 = x1;
}

__device__ __forceinline__ uint32_t jax_bits32(uint32_t k0, uint32_t k1, uint32_t i) {
  uint32_t b0, b1;
  threefry2x32(k0, k1, 0u, i, b0, b1);
  return b0 ^ b1;
}

// ---------------- one-time W transpose+cast for W2+W3 in one launch ----------------
__global__ __launch_bounds__(256) void transpose_w23(const float* __restrict__ W2,
                                                     const float* __restrict__ W3,
                                                     unsigned short* __restrict__ Wt2,
                                                     unsigned short* __restrict__ Wt3) {
  int idx = blockIdx.x * 256 + threadIdx.x;        // 0 .. 2*16384
  const float* W = (idx < 16384) ? W2 : W3;
  unsigned short* out = (idx < 16384) ? Wt2 : Wt3;
  int e = idx & 16383;
  int k = e >> 7, c = e & 127;
  out[c * 128 + k] = f2bf(W[e]);
}

// ---------------- MFMA GEMM core (LDS-staged, layer-1 + jk) ----------------
__device__ __forceinline__ void stage_Wt(const float* __restrict__ W,
                                         unsigned short* Wt, int tid) {
#pragma unroll
  for (int i = 0; i < 16; ++i) {            // 4096 float4 = 128 k x 32 cq
    int f4 = tid + i * 256;
    int k = f4 >> 5;
    int cq = f4 & 31;
    float4 w = *(const float4*)(W + k * 128 + cq * 4);
    Wt[(cq * 4 + 0) * LP + k] = f2bf(w.x);
    Wt[(cq * 4 + 1) * LP + k] = f2bf(w.y);
    Wt[(cq * 4 + 2) * LP + k] = f2bf(w.z);
    Wt[(cq * 4 + 3) * LP + k] = f2bf(w.w);
  }
}

__device__ __forceinline__ void mfma_compute_store(const unsigned short* At,
                                                   const unsigned short* Wt,
                                                   unsigned short* __restrict__ O,
                                                   int rbase, int tid) {
  const int lane = tid & 63;
  const int wv = tid >> 6;
  const int m = lane & 15;
  const int kg = lane >> 4;
  f32x4 acc0 = {0,0,0,0}, acc1 = {0,0,0,0}, acc2 = {0,0,0,0}, acc3 = {0,0,0,0};
  f32x4 acc4 = {0,0,0,0}, acc5 = {0,0,0,0}, acc6 = {0,0,0,0}, acc7 = {0,0,0,0};
  const unsigned short* Arow = At + (wv * 16 + m) * LP;
#pragma unroll
  for (int ks = 0; ks < 4; ++ks) {
    bf16x8 af = *(const bf16x8*)(Arow + ks * 32 + kg * 8);
#define MF(n, accn) { bf16x8 bfr = *(const bf16x8*)(Wt + (n * 16 + m) * LP + ks * 32 + kg * 8); \
    accn = __builtin_amdgcn_mfma_f32_16x16x32_bf16(af, bfr, accn, 0, 0, 0); }
    MF(0, acc0) MF(1, acc1) MF(2, acc2) MF(3, acc3)
    MF(4, acc4) MF(5, acc5) MF(6, acc6) MF(7, acc7)
#undef MF
  }
#define ST(n, accn) {                                                       \
  _Pragma("unroll")                                                         \
  for (int j = 0; j < 4; ++j) {                                             \
    int grow = rbase + wv * 16 + kg * 4 + j;                                \
    if (grow < N_NODES) O[(size_t)grow * 128 + n * 16 + m] = f2bf(accn[j]); \
  } }
  ST(0, acc0) ST(1, acc1) ST(2, acc2) ST(3, acc3)
  ST(4, acc4) ST(5, acc5) ST(6, acc6) ST(7, acc7)
#undef ST
}

// plain (layer 1): O = bf16(A) @ bf16(W), O stored bf16
__global__ __launch_bounds__(256) void gemm_mfma(const float* __restrict__ A,
                                                 const float* __restrict__ W,
                                                 unsigned short* __restrict__ O) {
  __shared__ __align__(16) unsigned short Wt[128 * LP];
  __shared__ __align__(16) unsigned short At[64 * LP];
  const int tid = threadIdx.x;
  const int rbase = blockIdx.x * 64;
  stage_Wt(W, Wt, tid);
#pragma unroll
  for (int i = 0; i < 8; ++i) {             // 2048 float4 = 64 r x 32 cq
    int f4 = tid + i * 256;
    int r = f4 >> 5;
    int cq = f4 & 31;
    int grow = rbase + r;
    if (grow >= N_NODES) grow = N_NODES - 1;
    float4 a = *(const float4*)(A + (size_t)grow * 128 + cq * 4);
    uint32_t p0 = (uint32_t)f2bf(a.x) | ((uint32_t)f2bf(a.y) << 16);
    uint32_t p1 = (uint32_t)f2bf(a.z) | ((uint32_t)f2bf(a.w) << 16);
    *(uint2*)(At + r * LP + cq * 4) = make_uint2(p0, p1);
  }
  __syncthreads();
  mfma_compute_store(At, Wt, O, rbase, tid);
}

// fused (layers 2,3): LDS-FREE main body. Block prologue reduces the NBUCKx256
// stats partials -> ss in LDS. BN(scale/shift)+ReLU -> Xb bf16; dropout (threefry)
// -> bf16 A-fragments; B from pre-transposed global bf16 Wt[c][k] (pitch 128).
__global__ __launch_bounds__(256) void gemm_mfma_fused(const float* __restrict__ AGG,
                                                       const float* __restrict__ partials,
                                                       const float* __restrict__ g,
                                                       const float* __restrict__ bt,
                                                       const unsigned short* __restrict__ Wt,
                                                       unsigned int* __restrict__ Xb,
                                                       unsigned short* __restrict__ O,
                                                       uint32_t k0, uint32_t k1) {
  const int tid = threadIdx.x;
  __shared__ float red[256];
  __shared__ float2 ssl[128];
  {
    float t0 = 0.f;
#pragma unroll
    for (int b = 0; b < NBUCK; ++b) t0 += partials[b * 256 + tid];
    red[tid] = t0;
    __syncthreads();
    if (tid < 128) {
      float s = red[tid], q = red[128 + tid];
      float mu = s * (1.0f / N_NODES);
      float var = fmaxf(q * (1.0f / N_NODES) - mu * mu, 0.f);
      float inv = rsqrtf(var + BN_EPS);
      float sc = g[tid] * inv;
      ssl[tid] = make_float2(sc, bt[tid] - mu * sc);
    }
    __syncthreads();
  }
  const int lane = tid & 63;
  const int wv = tid >> 6;
  const int m = lane & 15;
  const int kg = lane >> 4;
  const int rbase = blockIdx.x * 64;
  int row = rbase + wv * 16 + m;
  bool valid = row < N_NODES;
  int rowc = valid ? row : N_NODES - 1;
  const float* Ar = AGG + (size_t)rowc * 128 + kg * 8;
  bf16x8 af0, af1, af2, af3;
#define LDF(ksc, afk) {                                                        \
    float4 a0 = *(const float4*)(Ar + ksc);                                    \
    float4 a1 = *(const float4*)(Ar + ksc + 4);                                \
    const float2* ssp = ssl + ksc + kg * 8;                                    \
    float av[8] = {a0.x, a0.y, a0.z, a0.w, a1.x, a1.y, a1.z, a1.w};            \
    unsigned short yb[8];                                                      \
    _Pragma("unroll")                                                          \
    for (int jj = 0; jj < 8; ++jj) {                                           \
      float2 sv = ssp[jj];                                                     \
      float yv = fmaxf(fmaf(av[jj], sv.x, sv.y), 0.f);                         \
      uint32_t bits = jax_bits32(k0, k1, (uint32_t)(rowc * 128 + ksc + kg * 8 + jj)); \
      yb[jj] = f2bf(yv);                                                       \
      afk[jj] = (short)f2bf((bits & 0x80000000u) ? 0.f : 2.f * yv);            \
    }                                                                          \
    if (valid) {                                                               \
      uint4 yp;                                                                \
      yp.x = (uint32_t)yb[0] | ((uint32_t)yb[1] << 16);                        \
      yp.y = (uint32_t)yb[2] | ((uint32_t)yb[3] << 16);                        \
      yp.z = (uint32_t)yb[4] | ((uint32_t)yb[5] << 16);                        \
      yp.w = (uint32_t)yb[6] | ((uint32_t)yb[7] << 16);                        \
      *(uint4*)(Xb + (size_t)row * 64 + (ksc) / 2 + kg * 4) = yp;              \
    } }
  LDF(0, af0) LDF(32, af1) LDF(64, af2) LDF(96, af3)
#undef LDF
  f32x4 acc0 = {0,0,0,0}, acc1 = {0,0,0,0}, acc2 = {0,0,0,0}, acc3 = {0,0,0,0};
  f32x4 acc4 = {0,0,0,0}, acc5 = {0,0,0,0}, acc6 = {0,0,0,0}, acc7 = {0,0,0,0};
  const unsigned short* Wm = Wt + m * 128 + kg * 8;
#define MFMA_ALL(afk, ksc)                                                              \
  acc0 = __builtin_amdgcn_mfma_f32_16x16x32_bf16(afk, *(const bf16x8*)(Wm + 0 * 2048 + ksc), acc0, 0, 0, 0); \
  acc1 = __builtin_amdgcn_mfma_f32_16x16x32_bf16(afk, *(const bf16x8*)(Wm + 1 * 2048 + ksc), acc1, 0, 0, 0); \
  acc2 = __builtin_amdgcn_mfma_f32_16x16x32_bf16(afk, *(const bf16x8*)(Wm + 2 * 2048 + ksc), acc2, 0, 0, 0); \
  acc3 = __builtin_amdgcn_mfma_f32_16x16x32_bf16(afk, *(const bf16x8*)(Wm + 3 * 2048 + ksc), acc3, 0, 0, 0); \
  acc4 = __builtin_amdgcn_mfma_f32_16x16x32_bf16(afk, *(const bf16x8*)(Wm + 4 * 2048 + ksc), acc4, 0, 0, 0); \
  acc5 = __builtin_amdgcn_mfma_f32_16x16x32_bf16(afk, *(const bf16x8*)(Wm + 5 * 2048 + ksc), acc5, 0, 0, 0); \
  acc6 = __builtin_amdgcn_mfma_f32_16x16x32_bf16(afk, *(const bf16x8*)(Wm + 6 * 2048 + ksc), acc6, 0, 0, 0); \
  acc7 = __builtin_amdgcn_mfma_f32_16x16x32_bf16(afk, *(const bf16x8*)(Wm + 7 * 2048 + ksc), acc7, 0, 0, 0);
  MFMA_ALL(af0, 0) MFMA_ALL(af1, 32) MFMA_ALL(af2, 64) MFMA_ALL(af3, 96)
#undef MFMA_ALL
#pragma unroll
  for (int j = 0; j < 4; ++j) {
    int orow = rbase + wv * 16 + kg * 4 + j;
    if (orow < N_NODES) {
      unsigned short* op = O + (size_t)orow * 128 + m;
      op[0 * 16] = f2bf(acc0[j]); op[1 * 16] = f2bf(acc1[j]);
      op[2 * 16] = f2bf(acc2[j]); op[3 * 16] = f2bf(acc3[j]);
      op[4 * 16] = f2bf(acc4[j]); op[5 * 16] = f2bf(acc5[j]);
      op[6 * 16] = f2bf(acc6[j]); op[7 * 16] = f2bf(acc7[j]);
    }
  }
}

// ---------------- CSR build ----------------
__global__ __launch_bounds__(256) void csr_count(const int* __restrict__ ei,
                                                 int* __restrict__ cnt) {
  int e = blockIdx.x * 256 + threadIdx.x;
  if (e < N_EDGES) atomicAdd(&cnt[ei[e + N_EDGES]], 1);
}

__global__ __launch_bounds__(256) void scan_blocks(int* __restrict__ cnt,
                                                   int* __restrict__ bsum) {
  __shared__ int tmp[256];
  int tid = threadIdx.x;
  int i = blockIdx.x * 256 + tid;
  int v = (i < N_NODES) ? cnt[i] : 0;
  tmp[tid] = v;
  __syncthreads();
  for (int off = 1; off < 256; off <<= 1) {
    int t = (tid >= off) ? tmp[tid - off] : 0;
    __syncthreads();
    if (tid >= off) tmp[tid] += t;
    __syncthreads();
  }
  if (i < N_NODES) cnt[i] = tmp[tid] - v;
  if (tid == 255) bsum[blockIdx.x] = tmp[255];
}

__global__ __launch_bounds__(512) void scan_bsum(int* __restrict__ bsum, int nb) {
  __shared__ int tmp[512];
  int tid = threadIdx.x;
  int v = (tid < nb) ? bsum[tid] : 0;
  tmp[tid] = v;
  __syncthreads();
  for (int off = 1; off < 512; off <<= 1) {
    int t = (tid >= off) ? tmp[tid - off] : 0;
    __syncthreads();
    if (tid >= off) tmp[tid] += t;
    __syncthreads();
  }
  if (tid < nb) bsum[tid] = tmp[tid] - v;
}

__global__ __launch_bounds__(256) void add_offsets(int* __restrict__ cnt,
                                                   const int* __restrict__ bsum,
                                                   int* __restrict__ row_ptr) {
  int i = blockIdx.x * 256 + threadIdx.x;
  if (i < N_NODES) {
    int r = cnt[i] + bsum[blockIdx.x];
    row_ptr[i] = r;
    cnt[i] = r;
  }
  if (i == 0) row_ptr[N_NODES] = N_EDGES;
}

__global__ __launch_bounds__(256) void csr_fill(const int* __restrict__ ei,
                                                const float* __restrict__ ew,
                                                int* __restrict__ cursor,
                                                int2* __restrict__ edges) {
  int e = blockIdx.x * 256 + threadIdx.x;
  if (e < N_EDGES) {
    int d = ei[e + N_EDGES];
    int p = atomicAdd(&cursor[d], 1);
    edges[p] = make_int2(ei[e], __float_as_int(ew[e]));
  }
}

// ---------------- gather aggregation + (optional) fused BN stats
// HALF-WAVE per node: 32 lanes x uint2 (4 channels each); 8 nodes per 256-thr block.
// STATS: fp32 AGG + block LDS-reduce -> NBUCK-bucket atomic partials.
// !STATS (layer 3): AGG written bf16 (feeds only jk's max).
template <bool STATS>
__global__ __launch_bounds__(256) void gather_agg(const unsigned int* __restrict__ Hb,
                                                  const int* __restrict__ row_ptr,
                                                  const int2* __restrict__ edges,
                                                  const float* __restrict__ bias,
                                                  float* __restrict__ AGGf,
                                                  unsigned int* __restrict__ AGGb,
                                                  float* __restrict__ partials) {
  const int hw = threadIdx.x >> 5;          // 0..7 half-wave slot
  const int l32 = threadIdx.x & 31;         // lane within half-wave
  const int node = blockIdx.x * 8 + hw;
  float4 acc = *(const float4*)(bias + l32 * 4);
  const int beg = row_ptr[node];
  const int end = row_ptr[node + 1];
  const unsigned int* Hp = Hb + l32 * 2;
  int j = beg;
  for (; j + 3 < end; j += 4) {
    int2 e0 = edges[j + 0];
    int2 e1 = edges[j + 1];
    int2 e2 = edges[j + 2];
    int2 e3 = edges[j + 3];
    uint2 u0 = *(const uint2*)(Hp + (size_t)e0.x * 64);
    uint2 u1 = *(const uint2*)(Hp + (size_t)e1.x * 64);
    uint2 u2 = *(const uint2*)(Hp + (size_t)e2.x * 64);
    uint2 u3 = *(const uint2*)(Hp + (size_t)e3.x * 64);
    float w0 = __int_as_float(e0.y), w1 = __int_as_float(e1.y);
    float w2 = __int_as_float(e2.y), w3 = __int_as_float(e3.y);
    acc.x += w0 * bf_lo(u0.x) + w1 * bf_lo(u1.x) + w2 * bf_lo(u2.x) + w3 * bf_lo(u3.x);
    acc.y += w0 * bf_hi(u0.x) + w1 * bf_hi(u1.x) + w2 * bf_hi(u2.x) + w3 * bf_hi(u3.x);
    acc.z += w0 * bf_lo(u0.y) + w1 * bf_lo(u1.y) + w2 * bf_lo(u2.y) + w3 * bf_lo(u3.y);
    acc.w += w0 * bf_hi(u0.y) + w1 * bf_hi(u1.y) + w2 * bf_hi(u2.y) + w3 * bf_hi(u3.y);
  }
  for (; j < end; ++j) {
    int2 e = edges[j];
    uint2 u = *(const uint2*)(Hp + (size_t)e.x * 64);
    float w = __int_as_float(e.y);
    acc.x += w * bf_lo(u.x);
    acc.y += w * bf_hi(u.x);
    acc.z += w * bf_lo(u.y);
    acc.w += w * bf_hi(u.y);
  }
  if (STATS) {
    *(float4*)(AGGf + (size_t)node * 128 + l32 * 4) = acc;
    __shared__ float st[8][256];
    st[hw][l32 * 4 + 0] = acc.x;
    st[hw][l32 * 4 + 1] = acc.y;
    st[hw][l32 * 4 + 2] = acc.z;
    st[hw][l32 * 4 + 3] = acc.w;
    st[hw][128 + l32 * 4 + 0] = acc.x * acc.x;
    st[hw][128 + l32 * 4 + 1] = acc.y * acc.y;
    st[hw][128 + l32 * 4 + 2] = acc.z * acc.z;
    st[hw][128 + l32 * 4 + 3] = acc.w * acc.w;
    __syncthreads();
    float t = 0.f;
#pragma unroll
    for (int g = 0; g < 8; ++g) t += st[g][threadIdx.x];
    unsafeAtomicAdd(&partials[(blockIdx.x & (NBUCK - 1)) * 256 + threadIdx.x], t);
  } else {
    uint2 p;
    p.x = (uint32_t)f2bf(acc.x) | ((uint32_t)f2bf(acc.y) << 16);
    p.y = (uint32_t)f2bf(acc.z) | ((uint32_t)f2bf(acc.w) << 16);
    *(uint2*)(AGGb + (size_t)node * 64 + l32 * 2) = p;
  }
}

// ---------------- jk_final via MFMA: jk = max(bf16 X1, bf16 X2, bf16 X3);
// OUT = log_softmax(jk @ Wf + bf). 64 rows/block; A=jk bf16, B=Wf^T bf16 in LDS.
__global__ __launch_bounds__(256) void jk_final_mfma(const unsigned int* __restrict__ X1b,
                                                     const unsigned int* __restrict__ X2b,
                                                     const unsigned int* __restrict__ X3b,
                                                     const float* __restrict__ Wf,
                                                     const float* __restrict__ bf,
                                                     float* __restrict__ OUT) {
  __shared__ __align__(16) unsigned short Wt[64 * LP];   // Wt[col][k]
  __shared__ __align__(16) unsigned short At[64 * LP];   // jk rows bf16
  const int tid = threadIdx.x;
  const int rbase = blockIdx.x * 64;
#pragma unroll
  for (int i = 0; i < 8; ++i) {             // 2048 float4 = 128 k x 16 cq
    int f4 = tid + i * 256;
    int k = f4 >> 4;
    int cq = f4 & 15;
    float4 w = *(const float4*)(Wf + k * 64 + cq * 4);
    Wt[(cq * 4 + 0) * LP + k] = f2bf(w.x);
    Wt[(cq * 4 + 1) * LP + k] = f2bf(w.y);
    Wt[(cq * 4 + 2) * LP + k] = f2bf(w.z);
    Wt[(cq * 4 + 3) * LP + k] = f2bf(w.w);
  }
#pragma unroll
  for (int i = 0; i < 8; ++i) {             // 2048 quads = 64 r x 32 cq
    int f4 = tid + i * 256;
    int r = f4 >> 5;
    int cq = f4 & 31;
    int grow = rbase + r;
    if (grow >= N_NODES) grow = N_NODES - 1;
    uint2 u1 = *(const uint2*)(X1b + (size_t)grow * 64 + cq * 2);
    uint2 u2 = *(const uint2*)(X2b + (size_t)grow * 64 + cq * 2);
    uint2 u3 = *(const uint2*)(X3b + (size_t)grow * 64 + cq * 2);
    float m0 = fmaxf(fmaxf(bf_lo(u1.x), bf_lo(u2.x)), bf_lo(u3.x));
    float m1 = fmaxf(fmaxf(bf_hi(u1.x), bf_hi(u2.x)), bf_hi(u3.x));
    float m2 = fmaxf(fmaxf(bf_lo(u1.y), bf_lo(u2.y)), bf_lo(u3.y));
    float m3 = fmaxf(fmaxf(bf_hi(u1.y), bf_hi(u2.y)), bf_hi(u3.y));
    uint32_t p0 = (uint32_t)f2bf(m0) | ((uint32_t)f2bf(m1) << 16);
    uint32_t p1 = (uint32_t)f2bf(m2) | ((uint32_t)f2bf(m3) << 16);
    *(uint2*)(At + r * LP + cq * 4) = make_uint2(p0, p1);
  }
  __syncthreads();
  const int lane = tid & 63;
  const int wv = tid >> 6;
  const int m = lane & 15;
  const int kg = lane >> 4;
  f32x4 acc0 = {0,0,0,0}, acc1 = {0,0,0,0}, acc2 = {0,0,0,0}, acc3 = {0,0,0,0};
  const unsigned short* Arow = At + (wv * 16 + m) * LP;
#pragma unroll
  for (int ks = 0; ks < 4; ++ks) {
    bf16x8 af = *(const bf16x8*)(Arow + ks * 32 + kg * 8);
#define MF(n, accn) { bf16x8 bfr = *(const bf16x8*)(Wt + (n * 16 + m) * LP + ks * 32 + kg * 8); \
    accn = __builtin_amdgcn_mfma_f32_16x16x32_bf16(af, bfr, accn, 0, 0, 0); }
    MF(0, acc0) MF(1, acc1) MF(2, acc2) MF(3, acc3)
#undef MF
  }
  float bf0 = bf[m], bf1 = bf[16 + m], bf2 = bf[32 + m], bf3 = bf[48 + m];
#pragma unroll
  for (int j = 0; j < 4; ++j) {
    int row = rbase + wv * 16 + kg * 4 + j;
    float v0 = acc0[j] + bf0;
    float v1 = acc1[j] + bf1;
    float v2 = acc2[j] + bf2;
    float v3 = acc3[j] + bf3;
    float M = fmaxf(fmaxf(v0, v1), fmaxf(v2, v3));
#pragma unroll
    for (int s = 1; s < 16; s <<= 1) M = fmaxf(M, __shfl_xor(M, s));
    float sum = expf(v0 - M) + expf(v1 - M) + expf(v2 - M) + expf(v3 - M);
#pragma unroll
    for (int s = 1; s < 16; s <<= 1) sum += __shfl_xor(sum, s);
    float ls = M + logf(sum);
    if (row < N_NODES) {
      float* o = OUT + (size_t)row * 64;
      o[m] = v0 - ls;
      o[16 + m] = v1 - ls;
      o[32 + m] = v2 - ls;
      o[48 + m] = v3 - ls;
    }
  }
}

extern "C" void kernel_launch(void* const* d_in, const int* in_sizes, int n_in,
                              void* d_out, int out_size, void* d_ws, size_t ws_size,
                              hipStream_t stream) {
  const float* x   = (const float*)d_in[0];
  const int*   ei  = (const int*)d_in[1];
  const float* ew  = (const float*)d_in[2];
  const float* W1  = (const float*)d_in[3];
  const float* b1  = (const float*)d_in[4];
  const float* W2  = (const float*)d_in[5];
  const float* b2  = (const float*)d_in[6];
  const float* W3  = (const float*)d_in[7];
  const float* b3  = (const float*)d_in[8];
  const float* g1  = (const float*)d_in[9];
  const float* bt1 = (const float*)d_in[10];
  const float* g2  = (const float*)d_in[11];
  const float* bt2 = (const float*)d_in[12];
  const float* Wf  = (const float*)d_in[13];
  const float* bfb = (const float*)d_in[14];
  float* out = (float*)d_out;

  float* B0 = (float*)d_ws;                // P buffer (bf16 ushort[NELEMS])
  float* B1 = B0 + NELEMS;                 // AGG fp32 (layers 1,2) / bf16 (layer 3)
  float* B2 = B1 + NELEMS;                 // X1 bf16 (uses half)
  float* B3 = B2 + NELEMS;                 // X2 bf16 (uses half)
  int2* edges = (int2*)(B3 + NELEMS);      // N_EDGES int2
  int* cursor = (int*)(edges + N_EDGES);   // N_NODES  (contiguous with partials for 1 memset)
  float* part1 = (float*)(cursor + N_NODES);   // NBUCK*256 floats
  float* part2 = part1 + NBUCK * 256;          // NBUCK*256 floats
  int* row_ptr = (int*)(part2 + NBUCK * 256);  // N_NODES+1
  int* bsum = row_ptr + N_NODES + 1;           // 512
  unsigned short* Wt2 = (unsigned short*)(bsum + 512);  // 128*128 bf16
  unsigned short* Wt3 = Wt2 + 128 * 128;
  unsigned short* P = (unsigned short*)B0;
  unsigned int* Pu = (unsigned int*)B0;
  unsigned int* X1b = (unsigned int*)B2;
  unsigned int* X2b = (unsigned int*)B3;
  unsigned int* AGG3b = (unsigned int*)B1;

  // JAX partitionable split of key(42)=(0,42): k_i = threefry(key, (0,i)) full pair
  uint32_t k1_0, k1_1, k2_0, k2_1;
  threefry2x32(0u, 42u, 0u, 0u, k1_0, k1_1);
  threefry2x32(0u, 42u, 0u, 1u, k2_0, k2_1);

  const int GEMM_GRID = (N_NODES + 63) / 64;       // 1563
  const int EDGE_GRID = (N_EDGES + 255) / 256;     // 2344
  const int NODE_GRID = (N_NODES + 255) / 256;     // 391
  const int AGG_GRID  = N_NODES / 8;               // 12500 (half-wave per node)
  const int FINAL_GRID = (N_NODES + 63) / 64;      // 1563
  const int TR_GRID = (2 * 128 * 128 + 255) / 256; // 128

  // ---- W2/W3 pre-transpose + CSR build + zero cursor+partials (one memset)
  transpose_w23<<<TR_GRID, 256, 0, stream>>>(W2, W3, Wt2, Wt3);
  hipMemsetAsync(cursor, 0, N_NODES * sizeof(int) + 2 * NBUCK * 256 * sizeof(float), stream);
  csr_count<<<EDGE_GRID, 256, 0, stream>>>(ei, cursor);
  scan_blocks<<<NODE_GRID, 256, 0, stream>>>(cursor, bsum);
  scan_bsum<<<1, 512, 0, stream>>>(bsum, NODE_GRID);
  add_offsets<<<NODE_GRID, 256, 0, stream>>>(cursor, bsum, row_ptr);
  csr_fill<<<EDGE_GRID, 256, 0, stream>>>(ei, ew, cursor, edges);

  // ---- layer 1: P = bf16(x@W1) ; AGG1 = gather(P)+b1 (+stats -> part1)
  gemm_mfma<<<GEMM_GRID, 256, 0, stream>>>(x, W1, P);
  gather_agg<true><<<AGG_GRID, 256, 0, stream>>>(Pu, row_ptr, edges, b1, B1, nullptr, part1);
  // ---- layer 2: fused [ss from part1] BN1+ReLU (-> X1 bf16) + dropout(k1) + GEMM W2 -> P
  gemm_mfma_fused<<<GEMM_GRID, 256, 0, stream>>>(B1, part1, g1, bt1, Wt2, X1b, P, k1_0, k1_1);
  gather_agg<true><<<AGG_GRID, 256, 0, stream>>>(Pu, row_ptr, edges, b2, B1, nullptr, part2);
  // ---- layer 3: fused [ss from part2] BN2+ReLU (-> X2 bf16) + dropout(k2) + GEMM W3 -> P
  gemm_mfma_fused<<<GEMM_GRID, 256, 0, stream>>>(B1, part2, g2, bt2, Wt3, X2b, P, k2_0, k2_1);
  gather_agg<false><<<AGG_GRID, 256, 0, stream>>>(Pu, row_ptr, edges, b3, nullptr, AGG3b, nullptr);
  // ---- JK max + final linear + log_softmax (MFMA, all-bf16 inputs)
  jk_final_mfma<<<FINAL_GRID, 256, 0, stream>>>(X1b, X2b, AGG3b, Wf, bfb, out);
}